// Round 7
// baseline (866.439 us; speedup 1.0000x reference)
//
#include <hip/hip_runtime.h>
#include <hip/hip_bf16.h>
#include <math.h>

#define HW 16384
#define Wd 128
#define NT_FFT 1024

// ---------------------------------------------------------------------------
// FFT amplitude-replacement kernel: one block per (tensor, b, c) plane.
// ---------------------------------------------------------------------------
__device__ __forceinline__ void fft_dim(float* re, float* im,
                                        const float* twc, const float* tws,
                                        int tid, int cols)
{
  for (int idx = tid; idx < 16384; idx += NT_FFT) {
    int f = idx & 127, g = idx >> 7;
    int r = cols ? f : g;
    int i = cols ? g : f;
    int j = (int)(__brev((unsigned)i) >> 25);
    if (i < j) {
      int e0 = cols ? (i * 128 + r) : (r * 128 + i);
      int e1 = cols ? (j * 128 + r) : (r * 128 + j);
      float t0 = re[e0]; re[e0] = re[e1]; re[e1] = t0;
      float t1 = im[e0]; im[e0] = im[e1]; im[e1] = t1;
    }
  }
  __syncthreads();
  for (int s = 0; s < 7; ++s) {
    int half = 1 << s;
    for (int idx = tid; idx < 8192; idx += NT_FFT) {
      int t, r;
      if (cols) { r = idx & 127; t = idx >> 7; }
      else      { r = idx >> 6;  t = idx & 63; }
      int pos = t & (half - 1);
      int i0 = ((t >> s) << (s + 1)) + pos;
      int i1 = i0 + half;
      int e0 = cols ? (i0 * 128 + r) : (r * 128 + i0);
      int e1 = cols ? (i1 * 128 + r) : (r * 128 + i1);
      int tj = pos << (6 - s);
      float cs = twc[tj], sn = tws[tj];
      float br = re[e1], bi = im[e1];
      float tr = br * cs - bi * sn;
      float ti = br * sn + bi * cs;
      float ar = re[e0], ai = im[e0];
      re[e0] = ar + tr; im[e0] = ai + ti;
      re[e1] = ar - tr; im[e1] = ai - ti;
    }
    __syncthreads();
  }
}

__global__ __launch_bounds__(NT_FFT) void fft_amp_kernel(
    const float* __restrict__ x, const float* __restrict__ xref,
    const float* __restrict__ amp, float* __restrict__ feat)
{
  __shared__ float sre[16384];
  __shared__ float sim[16384];
  __shared__ float twc[64];
  __shared__ float tws[64];
  int tid = threadIdx.x;
  int blk = blockIdx.x;          // 0..255
  int tensor = blk >> 7;         // 0 = x, 1 = x_ref
  int plane = blk & 127;         // b*64 + c
  const float* src = (tensor ? xref : x) + (size_t)plane * HW;
  if (tid < 64) {
    float ang = -6.283185307179586f * (float)tid / 128.f;
    float sn, cs;
    __sincosf(ang, &sn, &cs);
    twc[tid] = cs; tws[tid] = sn;
  }
  for (int i = tid; i < 16384; i += NT_FFT) { sre[i] = src[i]; sim[i] = 0.f; }
  __syncthreads();
  fft_dim(sre, sim, twc, tws, tid, 0);
  fft_dim(sre, sim, twc, tws, tid, 1);
  const float* ampb = amp + (size_t)plane * (128 * 65);
  for (int idx = tid; idx < 16384; idx += NT_FFT) {
    int ky = idx >> 7, kx = idx & 127;
    float A = (kx <= 64) ? ampb[ky * 65 + kx]
                         : ampb[((128 - ky) & 127) * 65 + (128 - kx)];
    float th = atan2f(sim[idx], sre[idx]);
    float sn, cs;
    __sincosf(th, &sn, &cs);
    sre[idx] = A * cs;
    sim[idx] = -A * sn;   // conj
  }
  __syncthreads();
  fft_dim(sre, sim, twc, tws, tid, 0);
  fft_dim(sre, sim, twc, tws, tid, 1);
  int b = plane >> 6, c = plane & 63;
  float* dst = feat + ((size_t)b * 128 + tensor * 64 + c) * HW;
  for (int i = tid; i < 16384; i += NT_FFT) dst[i] = sre[i] * (1.f / 16384.f);
}

// ---------------------------------------------------------------------------
// 3x3 conv v5: 4-deep software pipeline with STATIC register indexing
// (templated CIN, inner 4-phase unroll -> pend/tile indices compile-time).
// 8 co/block, 2-row strips. Schedule per phase t (ci = ci0+t):
//   barrier; ds_write tile[(t+1)&3] <- pend[(t+1)&3]; issue load ci+4 ->
//   pend[t]; compute tile[t].
// ---------------------------------------------------------------------------
template<int CIN>
__global__ __launch_bounds__(256) void conv3x3_v5(
    const float* __restrict__ in1, const float* __restrict__ in2, int csplit,
    const float* __restrict__ wt, const float* __restrict__ bias,
    float* __restrict__ out, int Cout, int cogroups, int lrelu)
{
  __shared__ float tile[4][4][136];
  int blk = blockIdx.x;
  int ystrip = blk & 63;
  int t2 = blk >> 6;
  int cog = t2 % cogroups;
  int b = t2 / cogroups;
  int cobase = cog << 3;
  int tid = threadIdx.x;
  int col = tid & 127;
  int rg = tid >> 7;
  int y0 = ystrip << 1;

  if (tid < 32) {
    int buf = tid >> 3, row = (tid >> 1) & 3, side = tid & 1;
    tile[buf][row][side ? 132 : 3] = 0.f;
  }

  int srow = tid >> 5;
  int sc4 = (tid & 31) << 2;
  int sy = y0 - 1 + srow;
  bool svalid = (unsigned)sy < 128u && tid < 128;
  size_t soff = (size_t)sy * Wd + sc4;

  // channel -> source pointer
  auto chp = [&](int c) -> const float* {
    return (c < csplit) ? in1 + ((size_t)b * csplit + c) * HW
                        : in2 + ((size_t)b * (CIN - csplit) + (c - csplit)) * HW;
  };

  float4 p0 = make_float4(0.f, 0.f, 0.f, 0.f);
  float4 p1 = p0, p2 = p0, p3 = p0;

  if (svalid) {
    p0 = *reinterpret_cast<const float4*>(chp(0) + soff);
    p1 = *reinterpret_cast<const float4*>(chp(1) + soff);
    p2 = *reinterpret_cast<const float4*>(chp(2) + soff);
    p3 = *reinterpret_cast<const float4*>(chp(3) + soff);
  }
  if (tid < 128)
    *reinterpret_cast<float4*>(&tile[0][srow][4 + sc4]) = p0;

  float acc[8];
  #pragma unroll
  for (int g = 0; g < 8; ++g) acc[g] = 0.f;

  for (int ci0 = 0; ci0 < CIN; ci0 += 4) {
    #pragma unroll
    for (int t = 0; t < 4; ++t) {
      int ci = ci0 + t;
      // uniform contiguous 72-dword weight load (scalar pipe)
      const float* wp = wt + ((size_t)ci * Cout + cobase) * 9;
      float wv[8][9];
      #pragma unroll
      for (int g = 0; g < 8; ++g)
        #pragma unroll
        for (int u = 0; u < 9; ++u) wv[g][u] = wp[g * 9 + u];

      __syncthreads();                  // tile[t] now visible
      // ds_write next buffer from its pending register (static index)
      if (ci + 1 < CIN && tid < 128) {
        float4 w4;
        switch ((t + 1) & 3) {
          case 0: w4 = p0; break;
          case 1: w4 = p1; break;
          case 2: w4 = p2; break;
          default: w4 = p3; break;
        }
        *reinterpret_cast<float4*>(&tile[(t + 1) & 3][srow][4 + sc4]) = w4;
      }
      // issue load for ci+4 into pend[t] (static register)
      if (ci + 4 < CIN && svalid) {
        float4 ld = *reinterpret_cast<const float4*>(chp(ci + 4) + soff);
        switch (t) {
          case 0: p0 = ld; break;
          case 1: p1 = ld; break;
          case 2: p2 = ld; break;
          default: p3 = ld; break;
        }
      }
      // compute from tile[t] (static LDS base)
      const float (*tb)[136] = tile[t];
      float tv[3][3];
      #pragma unroll
      for (int u = 0; u < 3; ++u)
        #pragma unroll
        for (int vv = 0; vv < 3; ++vv)
          tv[u][vv] = tb[rg + u][col + 3 + vv];
      #pragma unroll
      for (int g = 0; g < 8; ++g) {
        float s = 0.f;
        #pragma unroll
        for (int u = 0; u < 3; ++u)
          #pragma unroll
          for (int vv = 0; vv < 3; ++vv)
            s += tv[u][vv] * wv[g][u * 3 + vv];
        acc[g] += s;
      }
    }
  }

  #pragma unroll
  for (int g = 0; g < 8; ++g) {
    int co = cobase + g;
    if (co < Cout) {
      float v = acc[g] + bias[co];
      if (lrelu) v = v >= 0.f ? v : 0.1f * v;
      out[((size_t)b * Cout + co) * HW + (size_t)(y0 + rg) * Wd + col] = v;
    }
  }
}

// ---------------------------------------------------------------------------
// Transpose x[b][c][pix] -> xT[b][pix][c] (64x64 LDS tiles).
// ---------------------------------------------------------------------------
__global__ __launch_bounds__(256) void transpose_x(
    const float* __restrict__ x, float* __restrict__ xT)
{
  __shared__ float t[64][65];
  int blk = blockIdx.x;
  int b = blk >> 8;
  int pb = (blk & 255) << 6;
  int tid = threadIdx.x;
  int l = tid & 63;
  int g = tid >> 6;
  for (int it = 0; it < 16; ++it) {
    int c = g + it * 4;
    t[l][c] = x[((size_t)b * 64 + c) * HW + pb + l];
  }
  __syncthreads();
  for (int it = 0; it < 16; ++it) {
    int p = g + it * 4;
    xT[((size_t)b * HW + pb + p) * 64 + l] = t[p][l];
  }
}

// ---------------------------------------------------------------------------
// All weight prep: wdT[k][ci][co], w1T[co][co2], and the four transposed
// conv weights wt[ci][co][k].
// ---------------------------------------------------------------------------
__global__ __launch_bounds__(256) void prep_all(
    const float* __restrict__ wd, const float* __restrict__ w1,
    const float* __restrict__ w_off1, const float* __restrict__ w_off2,
    const float* __restrict__ w_om, const float* __restrict__ w_3x3,
    float* __restrict__ wdT, float* __restrict__ w1T,
    float* __restrict__ wt1, float* __restrict__ wt2,
    float* __restrict__ wtm, float* __restrict__ wt3)
{
  int i = blockIdx.x * 256 + threadIdx.x;
  if (i < 36864) {                    // wdT[k][ci][co]
    int k = i >> 12, ci = (i >> 6) & 63, co = i & 63;
    wdT[i] = wd[co * 576 + ci * 9 + k];
  } else if (i < 40960) {             // w1T[co][co2]
    int j = i - 36864;
    w1T[j] = w1[(j & 63) * 64 + (j >> 6)];
  } else if (i < 114688) {            // wt1: [128][64][9] from [64][128][9]
    int j = i - 40960;
    int k = j % 9, t = j / 9, co = t & 63, ci = t >> 6;
    wt1[j] = w_off1[((size_t)co * 128 + ci) * 9 + k];
  } else if (i < 151552) {            // wt2: [64][64][9] from [64][64][9]
    int j = i - 114688;
    int k = j % 9, t = j / 9, co = t & 63, ci = t >> 6;
    wt2[j] = w_off2[((size_t)co * 64 + ci) * 9 + k];
  } else if (i < 167168) {            // wtm: [64][27][9]+pad from [27][64][9]
    int j = i - 151552;
    if (j < 15552) {
      int k = j % 9, t = j / 9, co = t % 27, ci = t / 27;
      wtm[j] = w_om[((size_t)co * 64 + ci) * 9 + k];
    } else wtm[j] = 0.f;
  } else if (i < 240896) {            // wt3: [128][64][9] from [64][128][9]
    int j = i - 167168;
    int k = j % 9, t = j / 9, co = t & 63, ci = t >> 6;
    wt3[j] = w_3x3[((size_t)co * 128 + ci) * 9 + k];
  }
}

// ---------------------------------------------------------------------------
// Deformable conv + fused 1x1, register-tiled GEMM (unchanged).
// ---------------------------------------------------------------------------
__global__ __launch_bounds__(256) void deform_v2(
    const float* __restrict__ xT, const float* __restrict__ om,
    const float* __restrict__ wdT, const float* __restrict__ bd,
    const float* __restrict__ w1T, const float* __restrict__ b1,
    float* __restrict__ out)
{
  __shared__ float SM[9344];    // S[16][580]; later red[32][257] + Sd@8240
  __shared__ float wkf[4096];   // per-k weight panel [ci][co] xor-4 swizzled
  __shared__ int   gy0[144];
  __shared__ int   gx0[144];
  __shared__ float gwy[144];
  __shared__ float gwx[144];
  __shared__ float gm[144];

  int blk = blockIdx.x;
  int b = blk >> 10;
  int pb = (blk & 1023) << 4;
  int y = pb >> 7;
  int xb = pb & 127;
  int tid = threadIdx.x;

  if (tid < 144) {
    int k = tid >> 4, p = tid & 15;
    int xx = xb + p;
    const float* omb = om + (size_t)b * 27 * HW + (size_t)y * Wd + xx;
    float dy = omb[(2 * k) * HW];
    float dx = omb[(2 * k + 1) * HW];
    float mv = omb[(18 + k) * HW];
    mv = 1.f / (1.f + __expf(-mv));
    float py = (float)(y + (k / 3) - 1) + dy;
    float px = (float)(xx + (k % 3) - 1) + dx;
    float fy = floorf(py), fx = floorf(px);
    gy0[tid] = (int)fy; gx0[tid] = (int)fx;
    gwy[tid] = py - fy; gwx[tid] = px - fx;
    gm[tid] = mv;
  }
  __syncthreads();

  {
    int c = tid & 63, q = tid >> 6;
    const float* xbp = xT + ((size_t)b * HW) * 64 + c;
    for (int k = 0; k < 9; ++k) {
      #pragma unroll
      for (int i = 0; i < 4; ++i) {
        int p = q * 4 + i;
        int gi = k * 16 + p;
        int yy = gy0[gi], xc = gx0[gi];
        float wy = gwy[gi], wx = gwx[gi];
        bool y0v = (unsigned)yy < 128u, y1v = (unsigned)(yy + 1) < 128u;
        bool x0v = (unsigned)xc < 128u, x1v = (unsigned)(xc + 1) < 128u;
        long off = ((long)yy * Wd + xc) * 64;
        float v00 = (y0v && x0v) ? xbp[off] : 0.f;
        float v01 = (y0v && x1v) ? xbp[off + 64] : 0.f;
        float v10 = (y1v && x0v) ? xbp[off + Wd * 64] : 0.f;
        float v11 = (y1v && x1v) ? xbp[off + Wd * 64 + 64] : 0.f;
        float vs = (v00 * (1.f - wx) + v01 * wx) * (1.f - wy)
                 + (v10 * (1.f - wx) + v11 * wx) * wy;
        SM[p * 580 + k * 64 + c] = vs * gm[gi];
      }
    }
  }
  __syncthreads();

  int pg = tid & 3;
  int cg = (tid >> 2) & 7;
  int r = tid >> 5;
  int swz = (r & 1) << 2;
  float acc[4][8];
  #pragma unroll
  for (int i = 0; i < 4; ++i)
    #pragma unroll
    for (int j = 0; j < 8; ++j) acc[i][j] = 0.f;

  for (int k = 0; k < 9; ++k) {
    __syncthreads();
    #pragma unroll
    for (int t = 0; t < 4; ++t) {
      int fi = (tid + t * 256) * 4;
      int ci = fi >> 6, col = fi & 63;
      int sw = ((ci >> 3) & 1) << 2;
      float4 v = *reinterpret_cast<const float4*>(wdT + k * 4096 + fi);
      *reinterpret_cast<float4*>(&wkf[ci * 64 + (col ^ sw)]) = v;
    }
    __syncthreads();
    #pragma unroll
    for (int q4 = 0; q4 < 2; ++q4) {
      int cib = r * 8 + q4 * 4;
      float svf[4][4];
      #pragma unroll
      for (int i = 0; i < 4; ++i) {
        float4 t4 = *reinterpret_cast<const float4*>(
            &SM[(pg * 4 + i) * 580 + k * 64 + cib]);
        svf[i][0] = t4.x; svf[i][1] = t4.y; svf[i][2] = t4.z; svf[i][3] = t4.w;
      }
      float wlof[4][4], whif[4][4];
      #pragma unroll
      for (int jj = 0; jj < 4; ++jj) {
        const float* wrow = &wkf[(cib + jj) * 64];
        float4 a = *reinterpret_cast<const float4*>(&wrow[(cg * 8) ^ swz]);
        float4 c4 = *reinterpret_cast<const float4*>(&wrow[(cg * 8 + 4) ^ swz]);
        wlof[jj][0] = a.x; wlof[jj][1] = a.y; wlof[jj][2] = a.z; wlof[jj][3] = a.w;
        whif[jj][0] = c4.x; whif[jj][1] = c4.y; whif[jj][2] = c4.z; whif[jj][3] = c4.w;
      }
      #pragma unroll
      for (int i = 0; i < 4; ++i) {
        #pragma unroll
        for (int jj = 0; jj < 4; ++jj) {
          float s = svf[i][jj];
          #pragma unroll
          for (int j = 0; j < 4; ++j) {
            acc[i][j]     += s * wlof[jj][j];
            acc[i][j + 4] += s * whif[jj][j];
          }
        }
      }
    }
  }
  __syncthreads();

  {
    int T = cg * 4 + pg;
    float* rb = &SM[T * 257 + r * 32];
    #pragma unroll
    for (int i = 0; i < 4; ++i)
      #pragma unroll
      for (int j = 0; j < 8; ++j)
        rb[i * 8 + j] = acc[i][j];
  }
  __syncthreads();

  int p = tid & 15, cg2 = tid >> 4;
  {
    int T = (cg2 >> 1) * 4 + (p >> 2);
    int ebase = (p & 3) * 8 + (cg2 & 1) * 4;
    #pragma unroll
    for (int j = 0; j < 4; ++j) {
      float s = 0.f;
      #pragma unroll
      for (int rr = 0; rr < 8; ++rr)
        s += SM[T * 257 + rr * 32 + ebase + j];
      s += bd[cg2 * 4 + j];
      s = s >= 0.f ? s : 0.1f * s;
      SM[8240 + p * 65 + cg2 * 4 + j] = s;
    }
  }
  __syncthreads();

  {
    float a0 = b1[cg2 * 4], a1 = b1[cg2 * 4 + 1];
    float a2 = b1[cg2 * 4 + 2], a3 = b1[cg2 * 4 + 3];
    const float* wp = w1T + cg2 * 4;
    const float* sd = &SM[8240 + p * 65];
    #pragma unroll 8
    for (int co = 0; co < 64; ++co) {
      float dv = sd[co];
      float4 wv = *reinterpret_cast<const float4*>(wp + co * 64);
      a0 += dv * wv.x; a1 += dv * wv.y; a2 += dv * wv.z; a3 += dv * wv.w;
    }
    float* ob = out + ((size_t)b * 64 + cg2 * 4) * HW + pb + p;
    float rv[4] = {a0, a1, a2, a3};
    #pragma unroll
    for (int j = 0; j < 4; ++j) {
      float v = rv[j];
      ob[(size_t)j * HW] = v >= 0.f ? v : 0.1f * v;
    }
  }
}

// ---------------------------------------------------------------------------
extern "C" void kernel_launch(void* const* d_in, const int* in_sizes, int n_in,
                              void* d_out, int out_size, void* d_ws, size_t ws_size,
                              hipStream_t stream) {
  (void)in_sizes; (void)n_in; (void)out_size; (void)ws_size;
  const float* x       = (const float*)d_in[0];
  const float* x_ref   = (const float*)d_in[1];
  const float* amp     = (const float*)d_in[2];
  const float* new_inp = (const float*)d_in[3];
  const float* w_off1  = (const float*)d_in[4];
  const float* b_off1  = (const float*)d_in[5];
  const float* w_off2  = (const float*)d_in[6];
  const float* b_off2  = (const float*)d_in[7];
  const float* w_om    = (const float*)d_in[8];
  const float* b_om    = (const float*)d_in[9];
  const float* w_dcn   = (const float*)d_in[10];
  const float* b_dcn   = (const float*)d_in[11];
  const float* w_1x1   = (const float*)d_in[12];
  const float* b_1x1   = (const float*)d_in[13];
  const float* w_3x3   = (const float*)d_in[14];
  const float* b_3x3   = (const float*)d_in[15];
  float* out = (float*)d_out;

  float* ws    = (float*)d_ws;
  float* feat  = ws;                    // B*128*HW = 4,194,304 f
  float* buf1  = feat + 4194304;        // B*64*HW  = 2,097,152 f
  float* buf2  = buf1 + 2097152;        // B*64*HW
  float* ombuf = buf2 + 2097152;        // B*27*HW  = 884,736 f
  float* wreg  = ombuf + 884736;        // weight region, 240,896 f
  float* wdT   = wreg;                  // 36,864
  float* w1T   = wdT + 36864;           // 4,096
  float* wt1   = w1T + 4096;            // 73,728
  float* wt2   = wt1 + 73728;           // 36,864
  float* wtm   = wt2 + 36864;           // 15,616
  float* wt3   = wtm + 15616;           // 73,728
  float* xT    = feat;                  // alias: feat dead after conv1

  // 0) weight prep (independent of everything else)
  hipLaunchKernelGGL(prep_all, dim3(941), dim3(256), 0, stream,
                     w_dcn, w_1x1, w_off1, w_off2, w_om, w_3x3,
                     wdT, w1T, wt1, wt2, wtm, wt3);
  // 1) FFT amplitude swap -> feat
  hipLaunchKernelGGL(fft_amp_kernel, dim3(256), dim3(NT_FFT), 0, stream,
                     x, x_ref, amp, feat);
  // 2) conv1 (128->64) + lrelu
  hipLaunchKernelGGL((conv3x3_v5<128>), dim3(1024), dim3(256), 0, stream,
                     feat, (const float*)nullptr, 128, wt1, b_off1, buf1,
                     64, 8, 1);
  // 3) x transpose into now-dead feat region
  hipLaunchKernelGGL(transpose_x, dim3(512), dim3(256), 0, stream, x, xT);
  // 4) conv2 (64->64) + lrelu
  hipLaunchKernelGGL((conv3x3_v5<64>), dim3(1024), dim3(256), 0, stream,
                     buf1, (const float*)nullptr, 64, wt2, b_off2, buf2,
                     64, 8, 1);
  // 5) om conv (64->27)
  hipLaunchKernelGGL((conv3x3_v5<64>), dim3(512), dim3(256), 0, stream,
                     buf2, (const float*)nullptr, 64, wtm, b_om, ombuf,
                     27, 4, 0);
  // 6) deform + fused 1x1 -> buf1
  hipLaunchKernelGGL(deform_v2, dim3(2048), dim3(256), 0, stream,
                     xT, ombuf, wdT, b_dcn, w1T, b_1x1, buf1);
  // 7) final 3x3 conv on concat([d2, new_inp]) -> out
  hipLaunchKernelGGL((conv3x3_v5<128>), dim3(1024), dim3(256), 0, stream,
                     buf1, new_inp, 64, wt3, b_3x3, out, 64, 8, 0);
}

// Round 8
// 838.956 us; speedup vs baseline: 1.0328x; 1.0328x over previous
//
#include <hip/hip_runtime.h>
#include <hip/hip_bf16.h>
#include <math.h>

#define HW 16384
#define Wd 128
#define NT_FFT 1024

// ---------------------------------------------------------------------------
// FFT amplitude-replacement kernel: one block per (tensor, b, c) plane.
// ---------------------------------------------------------------------------
__device__ __forceinline__ void fft_dim(float* re, float* im,
                                        const float* twc, const float* tws,
                                        int tid, int cols)
{
  for (int idx = tid; idx < 16384; idx += NT_FFT) {
    int f = idx & 127, g = idx >> 7;
    int r = cols ? f : g;
    int i = cols ? g : f;
    int j = (int)(__brev((unsigned)i) >> 25);
    if (i < j) {
      int e0 = cols ? (i * 128 + r) : (r * 128 + i);
      int e1 = cols ? (j * 128 + r) : (r * 128 + j);
      float t0 = re[e0]; re[e0] = re[e1]; re[e1] = t0;
      float t1 = im[e0]; im[e0] = im[e1]; im[e1] = t1;
    }
  }
  __syncthreads();
  for (int s = 0; s < 7; ++s) {
    int half = 1 << s;
    for (int idx = tid; idx < 8192; idx += NT_FFT) {
      int t, r;
      if (cols) { r = idx & 127; t = idx >> 7; }
      else      { r = idx >> 6;  t = idx & 63; }
      int pos = t & (half - 1);
      int i0 = ((t >> s) << (s + 1)) + pos;
      int i1 = i0 + half;
      int e0 = cols ? (i0 * 128 + r) : (r * 128 + i0);
      int e1 = cols ? (i1 * 128 + r) : (r * 128 + i1);
      int tj = pos << (6 - s);
      float cs = twc[tj], sn = tws[tj];
      float br = re[e1], bi = im[e1];
      float tr = br * cs - bi * sn;
      float ti = br * sn + bi * cs;
      float ar = re[e0], ai = im[e0];
      re[e0] = ar + tr; im[e0] = ai + ti;
      re[e1] = ar - tr; im[e1] = ai - ti;
    }
    __syncthreads();
  }
}

__global__ __launch_bounds__(NT_FFT) void fft_amp_kernel(
    const float* __restrict__ x, const float* __restrict__ xref,
    const float* __restrict__ amp, float* __restrict__ feat)
{
  __shared__ float sre[16384];
  __shared__ float sim[16384];
  __shared__ float twc[64];
  __shared__ float tws[64];
  int tid = threadIdx.x;
  int blk = blockIdx.x;          // 0..255
  int tensor = blk >> 7;         // 0 = x, 1 = x_ref
  int plane = blk & 127;         // b*64 + c
  const float* src = (tensor ? xref : x) + (size_t)plane * HW;
  if (tid < 64) {
    float ang = -6.283185307179586f * (float)tid / 128.f;
    float sn, cs;
    __sincosf(ang, &sn, &cs);
    twc[tid] = cs; tws[tid] = sn;
  }
  for (int i = tid; i < 16384; i += NT_FFT) { sre[i] = src[i]; sim[i] = 0.f; }
  __syncthreads();
  fft_dim(sre, sim, twc, tws, tid, 0);
  fft_dim(sre, sim, twc, tws, tid, 1);
  const float* ampb = amp + (size_t)plane * (128 * 65);
  for (int idx = tid; idx < 16384; idx += NT_FFT) {
    int ky = idx >> 7, kx = idx & 127;
    float A = (kx <= 64) ? ampb[ky * 65 + kx]
                         : ampb[((128 - ky) & 127) * 65 + (128 - kx)];
    float th = atan2f(sim[idx], sre[idx]);
    float sn, cs;
    __sincosf(th, &sn, &cs);
    sre[idx] = A * cs;
    sim[idx] = -A * sn;   // conj
  }
  __syncthreads();
  fft_dim(sre, sim, twc, tws, tid, 0);
  fft_dim(sre, sim, twc, tws, tid, 1);
  int b = plane >> 6, c = plane & 63;
  float* dst = feat + ((size_t)b * 128 + tensor * 64 + c) * HW;
  for (int i = tid; i < 16384; i += NT_FFT) dst[i] = sre[i] * (1.f / 16384.f);
}

// ---------------------------------------------------------------------------
// 3x3 conv v6: barrier-free direct conv. No LDS. Each thread owns one
// output pixel (y,col) and 8 output channels; per ci it does 9 predicated
// coalesced global loads (L1/L2-served, neighbors overlap) + 72 FMAs with
// uniform scalar-loaded weights. Grid: B * cogroups * 64 row-strips.
// ---------------------------------------------------------------------------
template<int CIN>
__global__ __launch_bounds__(256) void conv3x3_v6(
    const float* __restrict__ in1, const float* __restrict__ in2, int csplit,
    const float* __restrict__ wt, const float* __restrict__ bias,
    float* __restrict__ out, int Cout, int cogroups, int lrelu)
{
  int blk = blockIdx.x;
  int ystrip = blk & 63;
  int t2 = blk >> 6;
  int cog = t2 % cogroups;
  int b = t2 / cogroups;
  int cobase = cog << 3;
  int tid = threadIdx.x;
  int col = tid & 127;
  int rg = tid >> 7;
  int y = (ystrip << 1) + rg;

  bool ym = y > 0, yp = y < 127;
  bool xm = col > 0, xp = col < 127;
  int base = y * Wd + col;

  float acc[8];
  #pragma unroll
  for (int g = 0; g < 8; ++g) acc[g] = 0.f;

  #pragma unroll 4
  for (int ci = 0; ci < CIN; ++ci) {
    const float* src = (ci < csplit)
        ? in1 + ((size_t)b * csplit + ci) * HW
        : in2 + ((size_t)b * (CIN - csplit) + (ci - csplit)) * HW;

    float v00 = (ym && xm) ? src[base - Wd - 1] : 0.f;
    float v01 =  ym        ? src[base - Wd]     : 0.f;
    float v02 = (ym && xp) ? src[base - Wd + 1] : 0.f;
    float v10 =  xm        ? src[base - 1]      : 0.f;
    float v11 =              src[base];
    float v12 =  xp        ? src[base + 1]      : 0.f;
    float v20 = (yp && xm) ? src[base + Wd - 1] : 0.f;
    float v21 =  yp        ? src[base + Wd]     : 0.f;
    float v22 = (yp && xp) ? src[base + Wd + 1] : 0.f;

    const float* wp = wt + ((size_t)ci * Cout + cobase) * 9;
    #pragma unroll
    for (int g = 0; g < 8; ++g) {
      float s = v00 * wp[g * 9 + 0] + v01 * wp[g * 9 + 1] + v02 * wp[g * 9 + 2]
              + v10 * wp[g * 9 + 3] + v11 * wp[g * 9 + 4] + v12 * wp[g * 9 + 5]
              + v20 * wp[g * 9 + 6] + v21 * wp[g * 9 + 7] + v22 * wp[g * 9 + 8];
      acc[g] += s;
    }
  }

  #pragma unroll
  for (int g = 0; g < 8; ++g) {
    int co = cobase + g;
    if (co < Cout) {
      float v = acc[g] + bias[co];
      if (lrelu) v = v >= 0.f ? v : 0.1f * v;
      out[((size_t)b * Cout + co) * HW + base] = v;
    }
  }
}

// ---------------------------------------------------------------------------
// Transpose x[b][c][pix] -> xT[b][pix][c] (64x64 LDS tiles).
// ---------------------------------------------------------------------------
__global__ __launch_bounds__(256) void transpose_x(
    const float* __restrict__ x, float* __restrict__ xT)
{
  __shared__ float t[64][65];
  int blk = blockIdx.x;
  int b = blk >> 8;
  int pb = (blk & 255) << 6;
  int tid = threadIdx.x;
  int l = tid & 63;
  int g = tid >> 6;
  for (int it = 0; it < 16; ++it) {
    int c = g + it * 4;
    t[l][c] = x[((size_t)b * 64 + c) * HW + pb + l];
  }
  __syncthreads();
  for (int it = 0; it < 16; ++it) {
    int p = g + it * 4;
    xT[((size_t)b * HW + pb + p) * 64 + l] = t[p][l];
  }
}

// ---------------------------------------------------------------------------
// All weight prep: wdT[k][ci][co], w1T[co][co2], and the four transposed
// conv weights wt[ci][co][k].
// ---------------------------------------------------------------------------
__global__ __launch_bounds__(256) void prep_all(
    const float* __restrict__ wd, const float* __restrict__ w1,
    const float* __restrict__ w_off1, const float* __restrict__ w_off2,
    const float* __restrict__ w_om, const float* __restrict__ w_3x3,
    float* __restrict__ wdT, float* __restrict__ w1T,
    float* __restrict__ wt1, float* __restrict__ wt2,
    float* __restrict__ wtm, float* __restrict__ wt3)
{
  int i = blockIdx.x * 256 + threadIdx.x;
  if (i < 36864) {                    // wdT[k][ci][co]
    int k = i >> 12, ci = (i >> 6) & 63, co = i & 63;
    wdT[i] = wd[co * 576 + ci * 9 + k];
  } else if (i < 40960) {             // w1T[co][co2]
    int j = i - 36864;
    w1T[j] = w1[(j & 63) * 64 + (j >> 6)];
  } else if (i < 114688) {            // wt1: [128][64][9] from [64][128][9]
    int j = i - 40960;
    int k = j % 9, t = j / 9, co = t & 63, ci = t >> 6;
    wt1[j] = w_off1[((size_t)co * 128 + ci) * 9 + k];
  } else if (i < 151552) {            // wt2: [64][64][9] from [64][64][9]
    int j = i - 114688;
    int k = j % 9, t = j / 9, co = t & 63, ci = t >> 6;
    wt2[j] = w_off2[((size_t)co * 64 + ci) * 9 + k];
  } else if (i < 167168) {            // wtm: [64][27][9]+pad from [27][64][9]
    int j = i - 151552;
    if (j < 15552) {
      int k = j % 9, t = j / 9, co = t % 27, ci = t / 27;
      wtm[j] = w_om[((size_t)co * 64 + ci) * 9 + k];
    } else wtm[j] = 0.f;
  } else if (i < 240896) {            // wt3: [128][64][9] from [64][128][9]
    int j = i - 167168;
    int k = j % 9, t = j / 9, co = t & 63, ci = t >> 6;
    wt3[j] = w_3x3[((size_t)co * 128 + ci) * 9 + k];
  }
}

// ---------------------------------------------------------------------------
// Deformable conv + fused 1x1, register-tiled GEMM (unchanged).
// ---------------------------------------------------------------------------
__global__ __launch_bounds__(256) void deform_v2(
    const float* __restrict__ xT, const float* __restrict__ om,
    const float* __restrict__ wdT, const float* __restrict__ bd,
    const float* __restrict__ w1T, const float* __restrict__ b1,
    float* __restrict__ out)
{
  __shared__ float SM[9344];    // S[16][580]; later red[32][257] + Sd@8240
  __shared__ float wkf[4096];   // per-k weight panel [ci][co] xor-4 swizzled
  __shared__ int   gy0[144];
  __shared__ int   gx0[144];
  __shared__ float gwy[144];
  __shared__ float gwx[144];
  __shared__ float gm[144];

  int blk = blockIdx.x;
  int b = blk >> 10;
  int pb = (blk & 1023) << 4;
  int y = pb >> 7;
  int xb = pb & 127;
  int tid = threadIdx.x;

  if (tid < 144) {
    int k = tid >> 4, p = tid & 15;
    int xx = xb + p;
    const float* omb = om + (size_t)b * 27 * HW + (size_t)y * Wd + xx;
    float dy = omb[(2 * k) * HW];
    float dx = omb[(2 * k + 1) * HW];
    float mv = omb[(18 + k) * HW];
    mv = 1.f / (1.f + __expf(-mv));
    float py = (float)(y + (k / 3) - 1) + dy;
    float px = (float)(xx + (k % 3) - 1) + dx;
    float fy = floorf(py), fx = floorf(px);
    gy0[tid] = (int)fy; gx0[tid] = (int)fx;
    gwy[tid] = py - fy; gwx[tid] = px - fx;
    gm[tid] = mv;
  }
  __syncthreads();

  {
    int c = tid & 63, q = tid >> 6;
    const float* xbp = xT + ((size_t)b * HW) * 64 + c;
    for (int k = 0; k < 9; ++k) {
      #pragma unroll
      for (int i = 0; i < 4; ++i) {
        int p = q * 4 + i;
        int gi = k * 16 + p;
        int yy = gy0[gi], xc = gx0[gi];
        float wy = gwy[gi], wx = gwx[gi];
        bool y0v = (unsigned)yy < 128u, y1v = (unsigned)(yy + 1) < 128u;
        bool x0v = (unsigned)xc < 128u, x1v = (unsigned)(xc + 1) < 128u;
        long off = ((long)yy * Wd + xc) * 64;
        float v00 = (y0v && x0v) ? xbp[off] : 0.f;
        float v01 = (y0v && x1v) ? xbp[off + 64] : 0.f;
        float v10 = (y1v && x0v) ? xbp[off + Wd * 64] : 0.f;
        float v11 = (y1v && x1v) ? xbp[off + Wd * 64 + 64] : 0.f;
        float vs = (v00 * (1.f - wx) + v01 * wx) * (1.f - wy)
                 + (v10 * (1.f - wx) + v11 * wx) * wy;
        SM[p * 580 + k * 64 + c] = vs * gm[gi];
      }
    }
  }
  __syncthreads();

  int pg = tid & 3;
  int cg = (tid >> 2) & 7;
  int r = tid >> 5;
  int swz = (r & 1) << 2;
  float acc[4][8];
  #pragma unroll
  for (int i = 0; i < 4; ++i)
    #pragma unroll
    for (int j = 0; j < 8; ++j) acc[i][j] = 0.f;

  for (int k = 0; k < 9; ++k) {
    __syncthreads();
    #pragma unroll
    for (int t = 0; t < 4; ++t) {
      int fi = (tid + t * 256) * 4;
      int ci = fi >> 6, col = fi & 63;
      int sw = ((ci >> 3) & 1) << 2;
      float4 v = *reinterpret_cast<const float4*>(wdT + k * 4096 + fi);
      *reinterpret_cast<float4*>(&wkf[ci * 64 + (col ^ sw)]) = v;
    }
    __syncthreads();
    #pragma unroll
    for (int q4 = 0; q4 < 2; ++q4) {
      int cib = r * 8 + q4 * 4;
      float svf[4][4];
      #pragma unroll
      for (int i = 0; i < 4; ++i) {
        float4 t4 = *reinterpret_cast<const float4*>(
            &SM[(pg * 4 + i) * 580 + k * 64 + cib]);
        svf[i][0] = t4.x; svf[i][1] = t4.y; svf[i][2] = t4.z; svf[i][3] = t4.w;
      }
      float wlof[4][4], whif[4][4];
      #pragma unroll
      for (int jj = 0; jj < 4; ++jj) {
        const float* wrow = &wkf[(cib + jj) * 64];
        float4 a = *reinterpret_cast<const float4*>(&wrow[(cg * 8) ^ swz]);
        float4 c4 = *reinterpret_cast<const float4*>(&wrow[(cg * 8 + 4) ^ swz]);
        wlof[jj][0] = a.x; wlof[jj][1] = a.y; wlof[jj][2] = a.z; wlof[jj][3] = a.w;
        whif[jj][0] = c4.x; whif[jj][1] = c4.y; whif[jj][2] = c4.z; whif[jj][3] = c4.w;
      }
      #pragma unroll
      for (int i = 0; i < 4; ++i) {
        #pragma unroll
        for (int jj = 0; jj < 4; ++jj) {
          float s = svf[i][jj];
          #pragma unroll
          for (int j = 0; j < 4; ++j) {
            acc[i][j]     += s * wlof[jj][j];
            acc[i][j + 4] += s * whif[jj][j];
          }
        }
      }
    }
  }
  __syncthreads();

  {
    int T = cg * 4 + pg;
    float* rb = &SM[T * 257 + r * 32];
    #pragma unroll
    for (int i = 0; i < 4; ++i)
      #pragma unroll
      for (int j = 0; j < 8; ++j)
        rb[i * 8 + j] = acc[i][j];
  }
  __syncthreads();

  int p = tid & 15, cg2 = tid >> 4;
  {
    int T = (cg2 >> 1) * 4 + (p >> 2);
    int ebase = (p & 3) * 8 + (cg2 & 1) * 4;
    #pragma unroll
    for (int j = 0; j < 4; ++j) {
      float s = 0.f;
      #pragma unroll
      for (int rr = 0; rr < 8; ++rr)
        s += SM[T * 257 + rr * 32 + ebase + j];
      s += bd[cg2 * 4 + j];
      s = s >= 0.f ? s : 0.1f * s;
      SM[8240 + p * 65 + cg2 * 4 + j] = s;
    }
  }
  __syncthreads();

  {
    float a0 = b1[cg2 * 4], a1 = b1[cg2 * 4 + 1];
    float a2 = b1[cg2 * 4 + 2], a3 = b1[cg2 * 4 + 3];
    const float* wp = w1T + cg2 * 4;
    const float* sd = &SM[8240 + p * 65];
    #pragma unroll 8
    for (int co = 0; co < 64; ++co) {
      float dv = sd[co];
      float4 wv = *reinterpret_cast<const float4*>(wp + co * 64);
      a0 += dv * wv.x; a1 += dv * wv.y; a2 += dv * wv.z; a3 += dv * wv.w;
    }
    float* ob = out + ((size_t)b * 64 + cg2 * 4) * HW + pb + p;
    float rv[4] = {a0, a1, a2, a3};
    #pragma unroll
    for (int j = 0; j < 4; ++j) {
      float v = rv[j];
      ob[(size_t)j * HW] = v >= 0.f ? v : 0.1f * v;
    }
  }
}

// ---------------------------------------------------------------------------
extern "C" void kernel_launch(void* const* d_in, const int* in_sizes, int n_in,
                              void* d_out, int out_size, void* d_ws, size_t ws_size,
                              hipStream_t stream) {
  (void)in_sizes; (void)n_in; (void)out_size; (void)ws_size;
  const float* x       = (const float*)d_in[0];
  const float* x_ref   = (const float*)d_in[1];
  const float* amp     = (const float*)d_in[2];
  const float* new_inp = (const float*)d_in[3];
  const float* w_off1  = (const float*)d_in[4];
  const float* b_off1  = (const float*)d_in[5];
  const float* w_off2  = (const float*)d_in[6];
  const float* b_off2  = (const float*)d_in[7];
  const float* w_om    = (const float*)d_in[8];
  const float* b_om    = (const float*)d_in[9];
  const float* w_dcn   = (const float*)d_in[10];
  const float* b_dcn   = (const float*)d_in[11];
  const float* w_1x1   = (const float*)d_in[12];
  const float* b_1x1   = (const float*)d_in[13];
  const float* w_3x3   = (const float*)d_in[14];
  const float* b_3x3   = (const float*)d_in[15];
  float* out = (float*)d_out;

  float* ws    = (float*)d_ws;
  float* feat  = ws;                    // B*128*HW = 4,194,304 f
  float* buf1  = feat + 4194304;        // B*64*HW  = 2,097,152 f
  float* buf2  = buf1 + 2097152;        // B*64*HW
  float* ombuf = buf2 + 2097152;        // B*27*HW  = 884,736 f
  float* wreg  = ombuf + 884736;        // weight region, 240,896 f
  float* wdT   = wreg;                  // 36,864
  float* w1T   = wdT + 36864;           // 4,096
  float* wt1   = w1T + 4096;            // 73,728
  float* wt2   = wt1 + 73728;           // 36,864
  float* wtm   = wt2 + 36864;           // 15,616
  float* wt3   = wtm + 15616;           // 73,728
  float* xT    = feat;                  // alias: feat dead after conv1

  // 0) weight prep (independent of everything else)
  hipLaunchKernelGGL(prep_all, dim3(941), dim3(256), 0, stream,
                     w_dcn, w_1x1, w_off1, w_off2, w_om, w_3x3,
                     wdT, w1T, wt1, wt2, wtm, wt3);
  // 1) FFT amplitude swap -> feat
  hipLaunchKernelGGL(fft_amp_kernel, dim3(256), dim3(NT_FFT), 0, stream,
                     x, x_ref, amp, feat);
  // 2) conv1 (128->64) + lrelu
  hipLaunchKernelGGL((conv3x3_v6<128>), dim3(1024), dim3(256), 0, stream,
                     feat, (const float*)nullptr, 128, wt1, b_off1, buf1,
                     64, 8, 1);
  // 3) x transpose into now-dead feat region
  hipLaunchKernelGGL(transpose_x, dim3(512), dim3(256), 0, stream, x, xT);
  // 4) conv2 (64->64) + lrelu
  hipLaunchKernelGGL((conv3x3_v6<64>), dim3(1024), dim3(256), 0, stream,
                     buf1, (const float*)nullptr, 64, wt2, b_off2, buf2,
                     64, 8, 1);
  // 5) om conv (64->27)
  hipLaunchKernelGGL((conv3x3_v6<64>), dim3(512), dim3(256), 0, stream,
                     buf2, (const float*)nullptr, 64, wtm, b_om, ombuf,
                     27, 4, 0);
  // 6) deform + fused 1x1 -> buf1
  hipLaunchKernelGGL(deform_v2, dim3(2048), dim3(256), 0, stream,
                     xT, ombuf, wdT, b_dcn, w1T, b_1x1, buf1);
  // 7) final 3x3 conv on concat([d2, new_inp]) -> out
  hipLaunchKernelGGL((conv3x3_v6<128>), dim3(1024), dim3(256), 0, stream,
                     buf1, new_inp, 64, wt3, b_3x3, out, 64, 8, 0);
}

// Round 10
// 519.123 us; speedup vs baseline: 1.6690x; 1.6161x over previous
//
#include <hip/hip_runtime.h>
#include <hip/hip_bf16.h>
#include <math.h>

#define HW 16384
#define Wd 128
#define NT_FFT 1024

// ---------------------------------------------------------------------------
// FFT amplitude-replacement kernel (unchanged): one block per plane.
// ---------------------------------------------------------------------------
__device__ __forceinline__ void fft_dim(float* re, float* im,
                                        const float* twc, const float* tws,
                                        int tid, int cols)
{
  for (int idx = tid; idx < 16384; idx += NT_FFT) {
    int f = idx & 127, g = idx >> 7;
    int r = cols ? f : g;
    int i = cols ? g : f;
    int j = (int)(__brev((unsigned)i) >> 25);
    if (i < j) {
      int e0 = cols ? (i * 128 + r) : (r * 128 + i);
      int e1 = cols ? (j * 128 + r) : (r * 128 + j);
      float t0 = re[e0]; re[e0] = re[e1]; re[e1] = t0;
      float t1 = im[e0]; im[e0] = im[e1]; im[e1] = t1;
    }
  }
  __syncthreads();
  for (int s = 0; s < 7; ++s) {
    int half = 1 << s;
    for (int idx = tid; idx < 8192; idx += NT_FFT) {
      int t, r;
      if (cols) { r = idx & 127; t = idx >> 7; }
      else      { r = idx >> 6;  t = idx & 63; }
      int pos = t & (half - 1);
      int i0 = ((t >> s) << (s + 1)) + pos;
      int i1 = i0 + half;
      int e0 = cols ? (i0 * 128 + r) : (r * 128 + i0);
      int e1 = cols ? (i1 * 128 + r) : (r * 128 + i1);
      int tj = pos << (6 - s);
      float cs = twc[tj], sn = tws[tj];
      float br = re[e1], bi = im[e1];
      float tr = br * cs - bi * sn;
      float ti = br * sn + bi * cs;
      float ar = re[e0], ai = im[e0];
      re[e0] = ar + tr; im[e0] = ai + ti;
      re[e1] = ar - tr; im[e1] = ai - ti;
    }
    __syncthreads();
  }
}

__global__ __launch_bounds__(NT_FFT) void fft_amp_kernel(
    const float* __restrict__ x, const float* __restrict__ xref,
    const float* __restrict__ amp, float* __restrict__ feat)
{
  __shared__ float sre[16384];
  __shared__ float sim[16384];
  __shared__ float twc[64];
  __shared__ float tws[64];
  int tid = threadIdx.x;
  int blk = blockIdx.x;          // 0..255
  int tensor = blk >> 7;         // 0 = x, 1 = x_ref
  int plane = blk & 127;         // b*64 + c
  const float* src = (tensor ? xref : x) + (size_t)plane * HW;
  if (tid < 64) {
    float ang = -6.283185307179586f * (float)tid / 128.f;
    float sn, cs;
    __sincosf(ang, &sn, &cs);
    twc[tid] = cs; tws[tid] = sn;
  }
  for (int i = tid; i < 16384; i += NT_FFT) { sre[i] = src[i]; sim[i] = 0.f; }
  __syncthreads();
  fft_dim(sre, sim, twc, tws, tid, 0);
  fft_dim(sre, sim, twc, tws, tid, 1);
  const float* ampb = amp + (size_t)plane * (128 * 65);
  for (int idx = tid; idx < 16384; idx += NT_FFT) {
    int ky = idx >> 7, kx = idx & 127;
    float A = (kx <= 64) ? ampb[ky * 65 + kx]
                         : ampb[((128 - ky) & 127) * 65 + (128 - kx)];
    float th = atan2f(sim[idx], sre[idx]);
    float sn, cs;
    __sincosf(th, &sn, &cs);
    sre[idx] = A * cs;
    sim[idx] = -A * sn;   // conj
  }
  __syncthreads();
  fft_dim(sre, sim, twc, tws, tid, 0);
  fft_dim(sre, sim, twc, tws, tid, 1);
  int b = plane >> 6, c = plane & 63;
  float* dst = feat + ((size_t)b * 128 + tensor * 64 + c) * HW;
  for (int i = tid; i < 16384; i += NT_FFT) dst[i] = sre[i] * (1.f / 16384.f);
}

// ---------------------------------------------------------------------------
// Transpose [b][C][HW] -> [b][HW][C] (pixel-major), 64-px chunks.
// ---------------------------------------------------------------------------
template<int C>
__global__ __launch_bounds__(256) void transpose_pm(
    const float* __restrict__ src, float* __restrict__ dst)
{
  __shared__ float t[64][C + 4];
  int blk = blockIdx.x;
  int b = blk >> 8;
  int pb = (blk & 255) << 6;
  int tid = threadIdx.x;
  int l = tid & 63;
  #pragma unroll
  for (int it = 0; it < C / 4; ++it) {
    int c = (tid >> 6) + it * 4;
    t[l][c] = src[((size_t)b * C + c) * HW + pb + l];
  }
  __syncthreads();
  constexpr int CG = C / 4;        // float4 groups per pixel
  constexpr int PXI = 256 / CG;    // pixels per iteration
  int c4 = (tid & (CG - 1)) * 4;
  int p0 = tid / CG;
  #pragma unroll
  for (int it = 0; it < 64 / PXI; ++it) {
    int p = p0 + it * PXI;
    float4 v = make_float4(t[p][c4], t[p][c4 + 1], t[p][c4 + 2], t[p][c4 + 3]);
    *reinterpret_cast<float4*>(&dst[((size_t)b * HW + pb + p) * C + c4]) = v;
  }
}

// ---------------------------------------------------------------------------
// Weight prep: wG*[k][ci][co] GEMM panels, wdT, w1T, padded om bias.
// ---------------------------------------------------------------------------
__global__ __launch_bounds__(256) void prep_gemm(
    const float* __restrict__ w_off1, const float* __restrict__ w_off2,
    const float* __restrict__ w_om, const float* __restrict__ w_3x3,
    const float* __restrict__ wd, const float* __restrict__ w1,
    const float* __restrict__ b_om,
    float* __restrict__ wG1, float* __restrict__ wG2,
    float* __restrict__ wGm, float* __restrict__ wG3,
    float* __restrict__ wdT, float* __restrict__ w1T, float* __restrict__ bmp)
{
  int i = blockIdx.x * 256 + threadIdx.x;
  if (i < 73728) {                       // wG1[9][128][64]
    int k = i >> 13, ci = (i >> 6) & 127, co = i & 63;
    wG1[i] = w_off1[((size_t)co * 128 + ci) * 9 + k];
  } else if (i < 110592) {               // wG2[9][64][64]
    int j = i - 73728;
    int k = j >> 12, ci = (j >> 6) & 63, co = j & 63;
    wG2[j] = w_off2[((size_t)co * 64 + ci) * 9 + k];
  } else if (i < 147456) {               // wGm[9][64][64], co>=27 zero
    int j = i - 110592;
    int k = j >> 12, ci = (j >> 6) & 63, co = j & 63;
    wGm[j] = (co < 27) ? w_om[((size_t)co * 64 + ci) * 9 + k] : 0.f;
  } else if (i < 221184) {               // wG3[9][128][64]
    int j = i - 147456;
    int k = j >> 13, ci = (j >> 6) & 127, co = j & 63;
    wG3[j] = w_3x3[((size_t)co * 128 + ci) * 9 + k];
  } else if (i < 258048) {               // wdT[k][ci][co]
    int j = i - 221184;
    int k = j >> 12, ci = (j >> 6) & 63, co = j & 63;
    wdT[j] = wd[co * 576 + ci * 9 + k];
  } else if (i < 262144) {               // w1T[co][co2]
    int j = i - 258048;
    w1T[j] = w1[(j & 63) * 64 + (j >> 6)];
  } else if (i < 262208) {
    int j = i - 262144;
    bmp[j] = (j < 27) ? b_om[j] : 0.f;
  }
}

// ---------------------------------------------------------------------------
// conv_gemm: 3x3 conv as im2col GEMM with the deform_v2 engine.
// Block: 16 pixels of one row x 64 co. Window (3x18xCIN) staged ONCE per
// block; weight panel [CIN][64] staged per k (xor-4 swizzled by (ci>>3)&1).
// Thread tile: 4px x 8co, 8-way ci-split, reduce via LDS.
// FIX vs r9: read-side swizzle derived from the ACTUAL row index
// (((cib+jj)>>3)&1) — the (r&1) shortcut is only valid for CIN=64.
// ---------------------------------------------------------------------------
template<int CIN, bool CONCAT, int OUTMODE>
__global__ __launch_bounds__(256) void conv_gemm(
    const float* __restrict__ a1, const float* __restrict__ a2,
    const float* __restrict__ wG, const float* __restrict__ bias,
    float* __restrict__ out, int lrelu)
{
  constexpr int CINP = CIN + 4;
  constexpr int WSZ = 3 * 20 * CINP;
  constexpr int SMSZ = (WSZ > 8224) ? WSZ : 8224;
  __shared__ float SM[SMSZ];
  __shared__ float wkf[CIN * 64];
  int blk = blockIdx.x;
  int b = blk >> 10;
  int pb = (blk & 1023) << 4;
  int y = pb >> 7;
  int xb = pb & 127;
  int tid = threadIdx.x;

  // stage im2col window: rows y-1..y+1, cols xb-1..xb+16, CIN channels
  {
    constexpr int CF = CIN / 4;
    constexpr int NF4 = 3 * 18 * CF;
    #pragma unroll
    for (int it = 0; it < (NF4 + 255) / 256; ++it) {
      int i = tid + it * 256;
      if (i < NF4) {
        int ci4 = (i & (CF - 1)) * 4;
        int t = i / CF;
        int col = t % 18;
        int row = t / 18;
        int yy = y - 1 + row;
        int xx = xb - 1 + col;
        float4 v = make_float4(0.f, 0.f, 0.f, 0.f);
        if ((unsigned)yy < 128u && (unsigned)xx < 128u) {
          size_t pix = (size_t)b * HW + (size_t)yy * Wd + xx;
          if (CONCAT)
            v = (ci4 < 64)
                ? *reinterpret_cast<const float4*>(a1 + pix * 64 + ci4)
                : *reinterpret_cast<const float4*>(a2 + pix * 64 + (ci4 - 64));
          else
            v = *reinterpret_cast<const float4*>(a1 + pix * CIN + ci4);
        }
        *reinterpret_cast<float4*>(&SM[(row * 20 + col) * CINP + ci4]) = v;
      }
    }
  }

  int pg = tid & 3;
  int cg = (tid >> 2) & 7;
  int r = tid >> 5;
  float acc[4][8];
  #pragma unroll
  for (int i = 0; i < 4; ++i)
    #pragma unroll
    for (int j = 0; j < 8; ++j) acc[i][j] = 0.f;

  for (int k = 0; k < 9; ++k) {
    if (k > 0) __syncthreads();          // previous panel fully consumed
    #pragma unroll
    for (int t = 0; t < CIN / 16; ++t) {
      int fi = (tid + t * 256) * 4;
      int ci = fi >> 6, col = fi & 63;
      int sw = ((ci >> 3) & 1) << 2;
      float4 v = *reinterpret_cast<const float4*>(wG + (size_t)k * CIN * 64 + fi);
      *reinterpret_cast<float4*>(&wkf[ci * 64 + (col ^ sw)]) = v;
    }
    __syncthreads();                     // covers window (k=0) + panel
    int dy = k / 3, dx = k - dy * 3;
    #pragma unroll
    for (int q4 = 0; q4 < CIN / 32; ++q4) {
      int cib = r * (CIN / 8) + q4 * 4;
      float svf[4][4];
      #pragma unroll
      for (int i = 0; i < 4; ++i) {
        float4 t4 = *reinterpret_cast<const float4*>(
            &SM[(dy * 20 + pg * 4 + i + dx) * CINP + cib]);
        svf[i][0] = t4.x; svf[i][1] = t4.y; svf[i][2] = t4.z; svf[i][3] = t4.w;
      }
      float wlo[4][4], whi[4][4];
      #pragma unroll
      for (int jj = 0; jj < 4; ++jj) {
        int sw = (((cib + jj) >> 3) & 1) << 2;   // row's true swizzle
        const float* wrow = &wkf[(cib + jj) * 64];
        float4 a = *reinterpret_cast<const float4*>(&wrow[(cg * 8) ^ sw]);
        float4 c4 = *reinterpret_cast<const float4*>(&wrow[(cg * 8 + 4) ^ sw]);
        wlo[jj][0] = a.x; wlo[jj][1] = a.y; wlo[jj][2] = a.z; wlo[jj][3] = a.w;
        whi[jj][0] = c4.x; whi[jj][1] = c4.y; whi[jj][2] = c4.z; whi[jj][3] = c4.w;
      }
      #pragma unroll
      for (int i = 0; i < 4; ++i)
        #pragma unroll
        for (int jj = 0; jj < 4; ++jj) {
          float s = svf[i][jj];
          #pragma unroll
          for (int j = 0; j < 4; ++j) {
            acc[i][j]     += s * wlo[jj][j];
            acc[i][j + 4] += s * whi[jj][j];
          }
        }
    }
  }
  __syncthreads();

  // reduce 8 ci-splits via LDS (window region dead)
  {
    int T = cg * 4 + pg;
    float* rb = &SM[T * 257 + r * 32];
    #pragma unroll
    for (int i = 0; i < 4; ++i)
      #pragma unroll
      for (int j = 0; j < 8; ++j)
        rb[i * 8 + j] = acc[i][j];
  }
  __syncthreads();
  int p = tid & 15, cg2 = tid >> 4;
  float res[4];
  {
    int T = (cg2 >> 1) * 4 + (p >> 2);
    int ebase = (p & 3) * 8 + (cg2 & 1) * 4;
    #pragma unroll
    for (int j = 0; j < 4; ++j) {
      float s = 0.f;
      #pragma unroll
      for (int rr = 0; rr < 8; ++rr)
        s += SM[T * 257 + rr * 32 + ebase + j];
      s += bias[cg2 * 4 + j];
      if (lrelu) s = s >= 0.f ? s : 0.1f * s;
      res[j] = s;
    }
  }
  if (OUTMODE == 0) {
    float4 o4 = make_float4(res[0], res[1], res[2], res[3]);
    *reinterpret_cast<float4*>(&out[((size_t)b * HW + pb + p) * 64 + cg2 * 4]) = o4;
  } else {
    #pragma unroll
    for (int j = 0; j < 4; ++j)
      out[((size_t)b * 64 + cg2 * 4 + j) * HW + pb + p] = res[j];
  }
}

// ---------------------------------------------------------------------------
// Deformable conv + fused 1x1. om pixel-major [b][hw][64(pad)]; output
// d2 pixel-major float4. GEMM core unchanged (CIN=64 swizzle is correct).
// ---------------------------------------------------------------------------
__global__ __launch_bounds__(256) void deform_v2(
    const float* __restrict__ xT, const float* __restrict__ omT,
    const float* __restrict__ wdT, const float* __restrict__ bd,
    const float* __restrict__ w1T, const float* __restrict__ b1,
    float* __restrict__ out)
{
  __shared__ float SM[9344];
  __shared__ float wkf[4096];
  __shared__ int   gy0[144];
  __shared__ int   gx0[144];
  __shared__ float gwy[144];
  __shared__ float gwx[144];
  __shared__ float gm[144];

  int blk = blockIdx.x;
  int b = blk >> 10;
  int pb = (blk & 1023) << 4;
  int y = pb >> 7;
  int xb = pb & 127;
  int tid = threadIdx.x;

  if (tid < 144) {
    int k = tid >> 4, p = tid & 15;
    int xx = xb + p;
    const float* omb = omT + ((size_t)b * HW + (size_t)y * Wd + xx) * 64;
    float dy = omb[2 * k];
    float dx = omb[2 * k + 1];
    float mv = omb[18 + k];
    mv = 1.f / (1.f + __expf(-mv));
    float py = (float)(y + (k / 3) - 1) + dy;
    float px = (float)(xx + (k % 3) - 1) + dx;
    float fy = floorf(py), fx = floorf(px);
    gy0[tid] = (int)fy; gx0[tid] = (int)fx;
    gwy[tid] = py - fy; gwx[tid] = px - fx;
    gm[tid] = mv;
  }
  __syncthreads();

  {
    int c = tid & 63, q = tid >> 6;
    const float* xbp = xT + ((size_t)b * HW) * 64 + c;
    for (int k = 0; k < 9; ++k) {
      #pragma unroll
      for (int i = 0; i < 4; ++i) {
        int p = q * 4 + i;
        int gi = k * 16 + p;
        int yy = gy0[gi], xc = gx0[gi];
        float wy = gwy[gi], wx = gwx[gi];
        bool y0v = (unsigned)yy < 128u, y1v = (unsigned)(yy + 1) < 128u;
        bool x0v = (unsigned)xc < 128u, x1v = (unsigned)(xc + 1) < 128u;
        long off = ((long)yy * Wd + xc) * 64;
        float v00 = (y0v && x0v) ? xbp[off] : 0.f;
        float v01 = (y0v && x1v) ? xbp[off + 64] : 0.f;
        float v10 = (y1v && x0v) ? xbp[off + Wd * 64] : 0.f;
        float v11 = (y1v && x1v) ? xbp[off + Wd * 64 + 64] : 0.f;
        float vs = (v00 * (1.f - wx) + v01 * wx) * (1.f - wy)
                 + (v10 * (1.f - wx) + v11 * wx) * wy;
        SM[p * 580 + k * 64 + c] = vs * gm[gi];
      }
    }
  }
  __syncthreads();

  int pg = tid & 3;
  int cg = (tid >> 2) & 7;
  int r = tid >> 5;
  int swz = (r & 1) << 2;
  float acc[4][8];
  #pragma unroll
  for (int i = 0; i < 4; ++i)
    #pragma unroll
    for (int j = 0; j < 8; ++j) acc[i][j] = 0.f;

  for (int k = 0; k < 9; ++k) {
    __syncthreads();
    #pragma unroll
    for (int t = 0; t < 4; ++t) {
      int fi = (tid + t * 256) * 4;
      int ci = fi >> 6, col = fi & 63;
      int sw = ((ci >> 3) & 1) << 2;
      float4 v = *reinterpret_cast<const float4*>(wdT + k * 4096 + fi);
      *reinterpret_cast<float4*>(&wkf[ci * 64 + (col ^ sw)]) = v;
    }
    __syncthreads();
    #pragma unroll
    for (int q4 = 0; q4 < 2; ++q4) {
      int cib = r * 8 + q4 * 4;
      float svf[4][4];
      #pragma unroll
      for (int i = 0; i < 4; ++i) {
        float4 t4 = *reinterpret_cast<const float4*>(
            &SM[(pg * 4 + i) * 580 + k * 64 + cib]);
        svf[i][0] = t4.x; svf[i][1] = t4.y; svf[i][2] = t4.z; svf[i][3] = t4.w;
      }
      float wlo[4][4], whi[4][4];
      #pragma unroll
      for (int jj = 0; jj < 4; ++jj) {
        const float* wrow = &wkf[(cib + jj) * 64];
        float4 a = *reinterpret_cast<const float4*>(&wrow[(cg * 8) ^ swz]);
        float4 c4 = *reinterpret_cast<const float4*>(&wrow[(cg * 8 + 4) ^ swz]);
        wlo[jj][0] = a.x; wlo[jj][1] = a.y; wlo[jj][2] = a.z; wlo[jj][3] = a.w;
        whi[jj][0] = c4.x; whi[jj][1] = c4.y; whi[jj][2] = c4.z; whi[jj][3] = c4.w;
      }
      #pragma unroll
      for (int i = 0; i < 4; ++i)
        #pragma unroll
        for (int jj = 0; jj < 4; ++jj) {
          float s = svf[i][jj];
          #pragma unroll
          for (int j = 0; j < 4; ++j) {
            acc[i][j]     += s * wlo[jj][j];
            acc[i][j + 4] += s * whi[jj][j];
          }
        }
    }
  }
  __syncthreads();

  {
    int T = cg * 4 + pg;
    float* rb = &SM[T * 257 + r * 32];
    #pragma unroll
    for (int i = 0; i < 4; ++i)
      #pragma unroll
      for (int j = 0; j < 8; ++j)
        rb[i * 8 + j] = acc[i][j];
  }
  __syncthreads();

  int p = tid & 15, cg2 = tid >> 4;
  {
    int T = (cg2 >> 1) * 4 + (p >> 2);
    int ebase = (p & 3) * 8 + (cg2 & 1) * 4;
    #pragma unroll
    for (int j = 0; j < 4; ++j) {
      float s = 0.f;
      #pragma unroll
      for (int rr = 0; rr < 8; ++rr)
        s += SM[T * 257 + rr * 32 + ebase + j];
      s += bd[cg2 * 4 + j];
      s = s >= 0.f ? s : 0.1f * s;
      SM[8240 + p * 65 + cg2 * 4 + j] = s;
    }
  }
  __syncthreads();

  {
    float a0 = b1[cg2 * 4], a1 = b1[cg2 * 4 + 1];
    float a2 = b1[cg2 * 4 + 2], a3 = b1[cg2 * 4 + 3];
    const float* wp = w1T + cg2 * 4;
    const float* sd = &SM[8240 + p * 65];
    #pragma unroll 8
    for (int co = 0; co < 64; ++co) {
      float dv = sd[co];
      float4 wv = *reinterpret_cast<const float4*>(wp + co * 64);
      a0 += dv * wv.x; a1 += dv * wv.y; a2 += dv * wv.z; a3 += dv * wv.w;
    }
    float r0 = a0 >= 0.f ? a0 : 0.1f * a0;
    float r1 = a1 >= 0.f ? a1 : 0.1f * a1;
    float r2 = a2 >= 0.f ? a2 : 0.1f * a2;
    float r3 = a3 >= 0.f ? a3 : 0.1f * a3;
    float4 o4 = make_float4(r0, r1, r2, r3);
    *reinterpret_cast<float4*>(
        &out[((size_t)b * HW + pb + p) * 64 + cg2 * 4]) = o4;
  }
}

// ---------------------------------------------------------------------------
extern "C" void kernel_launch(void* const* d_in, const int* in_sizes, int n_in,
                              void* d_out, int out_size, void* d_ws, size_t ws_size,
                              hipStream_t stream) {
  (void)in_sizes; (void)n_in; (void)out_size; (void)ws_size;
  const float* x       = (const float*)d_in[0];
  const float* x_ref   = (const float*)d_in[1];
  const float* amp     = (const float*)d_in[2];
  const float* new_inp = (const float*)d_in[3];
  const float* w_off1  = (const float*)d_in[4];
  const float* b_off1  = (const float*)d_in[5];
  const float* w_off2  = (const float*)d_in[6];
  const float* b_off2  = (const float*)d_in[7];
  const float* w_om    = (const float*)d_in[8];
  const float* b_om    = (const float*)d_in[9];
  const float* w_dcn   = (const float*)d_in[10];
  const float* b_dcn   = (const float*)d_in[11];
  const float* w_1x1   = (const float*)d_in[12];
  const float* b_1x1   = (const float*)d_in[13];
  const float* w_3x3   = (const float*)d_in[14];
  const float* b_3x3   = (const float*)d_in[15];
  float* out = (float*)d_out;

  float* ws = (float*)d_ws;
  float* A  = ws;                 // 16.8MB: feat; later xT(8.4) + niT(8.4)
  float* B  = A + 4194304;        // 16.8MB: featT; later omT(8.4)
  float* C  = B + 4194304;        // 8.4MB: buf1T; later d2T
  float* D  = C + 2097152;        // 8.4MB: buf2T
  float* W  = D + 2097152;        // weights: 262,208 floats
  float* feat  = A;
  float* xT    = A;
  float* niT   = A + 2097152;
  float* featT = B;
  float* omT   = B;
  float* buf1T = C;
  float* d2T   = C;
  float* buf2T = D;
  float* wG1 = W;                 // 73728
  float* wG2 = wG1 + 73728;       // 36864
  float* wGm = wG2 + 36864;       // 36864
  float* wG3 = wGm + 36864;       // 73728
  float* wdT = wG3 + 73728;       // 36864
  float* w1T = wdT + 36864;       // 4096
  float* bmp = w1T + 4096;        // 64

  // 0) weight prep
  hipLaunchKernelGGL(prep_gemm, dim3(1025), dim3(256), 0, stream,
                     w_off1, w_off2, w_om, w_3x3, w_dcn, w_1x1, b_om,
                     wG1, wG2, wGm, wG3, wdT, w1T, bmp);
  // 1) FFT amplitude swap -> feat (channel-major)
  hipLaunchKernelGGL(fft_amp_kernel, dim3(256), dim3(NT_FFT), 0, stream,
                     x, x_ref, amp, feat);
  // 2) feat -> featT (pixel-major)
  hipLaunchKernelGGL((transpose_pm<128>), dim3(512), dim3(256), 0, stream,
                     feat, featT);
  // 3) x -> xT, new_inp -> niT (into now-dead feat region)
  hipLaunchKernelGGL((transpose_pm<64>), dim3(512), dim3(256), 0, stream,
                     x, xT);
  hipLaunchKernelGGL((transpose_pm<64>), dim3(512), dim3(256), 0, stream,
                     new_inp, niT);
  // 4) conv1 (128->64) + lrelu
  hipLaunchKernelGGL((conv_gemm<128, false, 0>), dim3(2048), dim3(256), 0,
                     stream, featT, (const float*)nullptr, wG1, b_off1,
                     buf1T, 1);
  // 5) conv2 (64->64) + lrelu
  hipLaunchKernelGGL((conv_gemm<64, false, 0>), dim3(2048), dim3(256), 0,
                     stream, buf1T, (const float*)nullptr, wG2, b_off2,
                     buf2T, 1);
  // 6) om conv (64->64 padded, co>=27 zero) into featT region (dead)
  hipLaunchKernelGGL((conv_gemm<64, false, 0>), dim3(2048), dim3(256), 0,
                     stream, buf2T, (const float*)nullptr, wGm, bmp,
                     omT, 0);
  // 7) deform + fused 1x1 -> d2T (pixel-major, overwrites buf1T)
  hipLaunchKernelGGL(deform_v2, dim3(2048), dim3(256), 0, stream,
                     xT, omT, wdT, b_dcn, w1T, b_1x1, d2T);
  // 8) final conv on concat([d2T, niT]) -> out (channel-major)
  hipLaunchKernelGGL((conv_gemm<128, true, 1>), dim3(2048), dim3(256), 0,
                     stream, d2T, niT, wG3, b_3x3, out, 0);
}

// Round 11
// 494.525 us; speedup vs baseline: 1.7521x; 1.0497x over previous
//
#include <hip/hip_runtime.h>
#include <hip/hip_bf16.h>
#include <math.h>

#define HW 16384
#define Wd 128
#define NT_FFT 1024

// ---------------------------------------------------------------------------
// FFT amplitude-replacement kernel (unchanged): one block per plane.
// ---------------------------------------------------------------------------
__device__ __forceinline__ void fft_dim(float* re, float* im,
                                        const float* twc, const float* tws,
                                        int tid, int cols)
{
  for (int idx = tid; idx < 16384; idx += NT_FFT) {
    int f = idx & 127, g = idx >> 7;
    int r = cols ? f : g;
    int i = cols ? g : f;
    int j = (int)(__brev((unsigned)i) >> 25);
    if (i < j) {
      int e0 = cols ? (i * 128 + r) : (r * 128 + i);
      int e1 = cols ? (j * 128 + r) : (r * 128 + j);
      float t0 = re[e0]; re[e0] = re[e1]; re[e1] = t0;
      float t1 = im[e0]; im[e0] = im[e1]; im[e1] = t1;
    }
  }
  __syncthreads();
  for (int s = 0; s < 7; ++s) {
    int half = 1 << s;
    for (int idx = tid; idx < 8192; idx += NT_FFT) {
      int t, r;
      if (cols) { r = idx & 127; t = idx >> 7; }
      else      { r = idx >> 6;  t = idx & 63; }
      int pos = t & (half - 1);
      int i0 = ((t >> s) << (s + 1)) + pos;
      int i1 = i0 + half;
      int e0 = cols ? (i0 * 128 + r) : (r * 128 + i0);
      int e1 = cols ? (i1 * 128 + r) : (r * 128 + i1);
      int tj = pos << (6 - s);
      float cs = twc[tj], sn = tws[tj];
      float br = re[e1], bi = im[e1];
      float tr = br * cs - bi * sn;
      float ti = br * sn + bi * cs;
      float ar = re[e0], ai = im[e0];
      re[e0] = ar + tr; im[e0] = ai + ti;
      re[e1] = ar - tr; im[e1] = ai - ti;
    }
    __syncthreads();
  }
}

__global__ __launch_bounds__(NT_FFT) void fft_amp_kernel(
    const float* __restrict__ x, const float* __restrict__ xref,
    const float* __restrict__ amp, float* __restrict__ feat)
{
  __shared__ float sre[16384];
  __shared__ float sim[16384];
  __shared__ float twc[64];
  __shared__ float tws[64];
  int tid = threadIdx.x;
  int blk = blockIdx.x;          // 0..255
  int tensor = blk >> 7;         // 0 = x, 1 = x_ref
  int plane = blk & 127;         // b*64 + c
  const float* src = (tensor ? xref : x) + (size_t)plane * HW;
  if (tid < 64) {
    float ang = -6.283185307179586f * (float)tid / 128.f;
    float sn, cs;
    __sincosf(ang, &sn, &cs);
    twc[tid] = cs; tws[tid] = sn;
  }
  for (int i = tid; i < 16384; i += NT_FFT) { sre[i] = src[i]; sim[i] = 0.f; }
  __syncthreads();
  fft_dim(sre, sim, twc, tws, tid, 0);
  fft_dim(sre, sim, twc, tws, tid, 1);
  const float* ampb = amp + (size_t)plane * (128 * 65);
  for (int idx = tid; idx < 16384; idx += NT_FFT) {
    int ky = idx >> 7, kx = idx & 127;
    float A = (kx <= 64) ? ampb[ky * 65 + kx]
                         : ampb[((128 - ky) & 127) * 65 + (128 - kx)];
    float th = atan2f(sim[idx], sre[idx]);
    float sn, cs;
    __sincosf(th, &sn, &cs);
    sre[idx] = A * cs;
    sim[idx] = -A * sn;   // conj
  }
  __syncthreads();
  fft_dim(sre, sim, twc, tws, tid, 0);
  fft_dim(sre, sim, twc, tws, tid, 1);
  int b = plane >> 6, c = plane & 63;
  float* dst = feat + ((size_t)b * 128 + tensor * 64 + c) * HW;
  for (int i = tid; i < 16384; i += NT_FFT) dst[i] = sre[i] * (1.f / 16384.f);
}

// ---------------------------------------------------------------------------
// Transpose [b][C][HW] -> [b][HW][C] (pixel-major), 64-px chunks.
// ---------------------------------------------------------------------------
template<int C>
__global__ __launch_bounds__(256) void transpose_pm(
    const float* __restrict__ src, float* __restrict__ dst)
{
  __shared__ float t[64][C + 4];
  int blk = blockIdx.x;
  int b = blk >> 8;
  int pb = (blk & 255) << 6;
  int tid = threadIdx.x;
  int l = tid & 63;
  #pragma unroll
  for (int it = 0; it < C / 4; ++it) {
    int c = (tid >> 6) + it * 4;
    t[l][c] = src[((size_t)b * C + c) * HW + pb + l];
  }
  __syncthreads();
  constexpr int CG = C / 4;        // float4 groups per pixel
  constexpr int PXI = 256 / CG;    // pixels per iteration
  int c4 = (tid & (CG - 1)) * 4;
  int p0 = tid / CG;
  #pragma unroll
  for (int it = 0; it < 64 / PXI; ++it) {
    int p = p0 + it * PXI;
    float4 v = make_float4(t[p][c4], t[p][c4 + 1], t[p][c4 + 2], t[p][c4 + 3]);
    *reinterpret_cast<float4*>(&dst[((size_t)b * HW + pb + p) * C + c4]) = v;
  }
}

// ---------------------------------------------------------------------------
// Weight prep: wG*[k][ci][co] GEMM panels, wdT, w1T, padded om bias.
// ---------------------------------------------------------------------------
__global__ __launch_bounds__(256) void prep_gemm(
    const float* __restrict__ w_off1, const float* __restrict__ w_off2,
    const float* __restrict__ w_om, const float* __restrict__ w_3x3,
    const float* __restrict__ wd, const float* __restrict__ w1,
    const float* __restrict__ b_om,
    float* __restrict__ wG1, float* __restrict__ wG2,
    float* __restrict__ wGm, float* __restrict__ wG3,
    float* __restrict__ wdT, float* __restrict__ w1T, float* __restrict__ bmp)
{
  int i = blockIdx.x * 256 + threadIdx.x;
  if (i < 73728) {                       // wG1[9][128][64]
    int k = i >> 13, ci = (i >> 6) & 127, co = i & 63;
    wG1[i] = w_off1[((size_t)co * 128 + ci) * 9 + k];
  } else if (i < 110592) {               // wG2[9][64][64]
    int j = i - 73728;
    int k = j >> 12, ci = (j >> 6) & 63, co = j & 63;
    wG2[j] = w_off2[((size_t)co * 64 + ci) * 9 + k];
  } else if (i < 147456) {               // wGm[9][64][64], co>=27 zero
    int j = i - 110592;
    int k = j >> 12, ci = (j >> 6) & 63, co = j & 63;
    wGm[j] = (co < 27) ? w_om[((size_t)co * 64 + ci) * 9 + k] : 0.f;
  } else if (i < 221184) {               // wG3[9][128][64]
    int j = i - 147456;
    int k = j >> 13, ci = (j >> 6) & 127, co = j & 63;
    wG3[j] = w_3x3[((size_t)co * 128 + ci) * 9 + k];
  } else if (i < 258048) {               // wdT[k][ci][co]
    int j = i - 221184;
    int k = j >> 12, ci = (j >> 6) & 63, co = j & 63;
    wdT[j] = wd[co * 576 + ci * 9 + k];
  } else if (i < 262144) {               // w1T[co][co2]
    int j = i - 258048;
    w1T[j] = w1[(j & 63) * 64 + (j >> 6)];
  } else if (i < 262208) {
    int j = i - 262144;
    bmp[j] = (j < 27) ? b_om[j] : 0.f;
  }
}

// ---------------------------------------------------------------------------
// conv_gemm v2: 3x3 conv as im2col GEMM. Weights read DIRECTLY from global
// (L1/L2-resident panels, shared by all blocks) — no LDS weight staging, no
// per-k barriers. LDS = window only (33KB) -> 4 blocks/CU. 3 barriers total.
// ---------------------------------------------------------------------------
template<int CIN, bool CONCAT, int OUTMODE>
__global__ __launch_bounds__(256) void conv_gemm(
    const float* __restrict__ a1, const float* __restrict__ a2,
    const float* __restrict__ wG, const float* __restrict__ bias,
    float* __restrict__ out, int lrelu)
{
  constexpr int CINP = CIN + 4;
  constexpr int WSZ = 3 * 20 * CINP;
  constexpr int SMSZ = (WSZ > 8224) ? WSZ : 8224;
  __shared__ float SM[SMSZ];
  int blk = blockIdx.x;
  int b = blk >> 10;
  int pb = (blk & 1023) << 4;
  int y = pb >> 7;
  int xb = pb & 127;
  int tid = threadIdx.x;

  // stage im2col window: rows y-1..y+1, cols xb-1..xb+16, CIN channels
  {
    constexpr int CF = CIN / 4;
    constexpr int NF4 = 3 * 18 * CF;
    #pragma unroll
    for (int it = 0; it < (NF4 + 255) / 256; ++it) {
      int i = tid + it * 256;
      if (i < NF4) {
        int ci4 = (i & (CF - 1)) * 4;
        int t = i / CF;
        int col = t % 18;
        int row = t / 18;
        int yy = y - 1 + row;
        int xx = xb - 1 + col;
        float4 v = make_float4(0.f, 0.f, 0.f, 0.f);
        if ((unsigned)yy < 128u && (unsigned)xx < 128u) {
          size_t pix = (size_t)b * HW + (size_t)yy * Wd + xx;
          if (CONCAT)
            v = (ci4 < 64)
                ? *reinterpret_cast<const float4*>(a1 + pix * 64 + ci4)
                : *reinterpret_cast<const float4*>(a2 + pix * 64 + (ci4 - 64));
          else
            v = *reinterpret_cast<const float4*>(a1 + pix * CIN + ci4);
        }
        *reinterpret_cast<float4*>(&SM[(row * 20 + col) * CINP + ci4]) = v;
      }
    }
  }
  __syncthreads();

  int pg = tid & 3;
  int cg = (tid >> 2) & 7;
  int r = tid >> 5;
  float acc[4][8];
  #pragma unroll
  for (int i = 0; i < 4; ++i)
    #pragma unroll
    for (int j = 0; j < 8; ++j) acc[i][j] = 0.f;

  for (int k = 0; k < 9; ++k) {
    int dy = k / 3, dx = k - dy * 3;
    const float* wkp = wG + (size_t)k * CIN * 64;
    #pragma unroll
    for (int q4 = 0; q4 < CIN / 32; ++q4) {
      int cib = r * (CIN / 8) + q4 * 4;
      float svf[4][4];
      #pragma unroll
      for (int i = 0; i < 4; ++i) {
        float4 t4 = *reinterpret_cast<const float4*>(
            &SM[(dy * 20 + pg * 4 + i + dx) * CINP + cib]);
        svf[i][0] = t4.x; svf[i][1] = t4.y; svf[i][2] = t4.z; svf[i][3] = t4.w;
      }
      float wlo[4][4], whi[4][4];
      #pragma unroll
      for (int jj = 0; jj < 4; ++jj) {
        const float* wrow = wkp + (cib + jj) * 64 + cg * 8;
        float4 a = *reinterpret_cast<const float4*>(wrow);
        float4 c4 = *reinterpret_cast<const float4*>(wrow + 4);
        wlo[jj][0] = a.x; wlo[jj][1] = a.y; wlo[jj][2] = a.z; wlo[jj][3] = a.w;
        whi[jj][0] = c4.x; whi[jj][1] = c4.y; whi[jj][2] = c4.z; whi[jj][3] = c4.w;
      }
      #pragma unroll
      for (int i = 0; i < 4; ++i)
        #pragma unroll
        for (int jj = 0; jj < 4; ++jj) {
          float s = svf[i][jj];
          #pragma unroll
          for (int j = 0; j < 4; ++j) {
            acc[i][j]     += s * wlo[jj][j];
            acc[i][j + 4] += s * whi[jj][j];
          }
        }
    }
  }
  __syncthreads();

  // reduce 8 ci-splits via LDS (window region dead)
  {
    int T = cg * 4 + pg;
    float* rb = &SM[T * 257 + r * 32];
    #pragma unroll
    for (int i = 0; i < 4; ++i)
      #pragma unroll
      for (int j = 0; j < 8; ++j)
        rb[i * 8 + j] = acc[i][j];
  }
  __syncthreads();
  int p = tid & 15, cg2 = tid >> 4;
  float res[4];
  {
    int T = (cg2 >> 1) * 4 + (p >> 2);
    int ebase = (p & 3) * 8 + (cg2 & 1) * 4;
    #pragma unroll
    for (int j = 0; j < 4; ++j) {
      float s = 0.f;
      #pragma unroll
      for (int rr = 0; rr < 8; ++rr)
        s += SM[T * 257 + rr * 32 + ebase + j];
      s += bias[cg2 * 4 + j];
      if (lrelu) s = s >= 0.f ? s : 0.1f * s;
      res[j] = s;
    }
  }
  if (OUTMODE == 0) {
    float4 o4 = make_float4(res[0], res[1], res[2], res[3]);
    *reinterpret_cast<float4*>(&out[((size_t)b * HW + pb + p) * 64 + cg2 * 4]) = o4;
  } else {
    #pragma unroll
    for (int j = 0; j < 4; ++j)
      out[((size_t)b * 64 + cg2 * 4 + j) * HW + pb + p] = res[j];
  }
}

// ---------------------------------------------------------------------------
// Deformable conv + fused 1x1, v3: weights direct from global (no wkf LDS,
// no per-k barriers). LDS ~40KB -> 4 blocks/CU.
// ---------------------------------------------------------------------------
__global__ __launch_bounds__(256) void deform_v3(
    const float* __restrict__ xT, const float* __restrict__ omT,
    const float* __restrict__ wdT, const float* __restrict__ bd,
    const float* __restrict__ w1T, const float* __restrict__ b1,
    float* __restrict__ out)
{
  __shared__ float SM[9344];    // S[16][580]; later red[32][257] + Sd@8240
  __shared__ int   gy0[144];
  __shared__ int   gx0[144];
  __shared__ float gwy[144];
  __shared__ float gwx[144];
  __shared__ float gm[144];

  int blk = blockIdx.x;
  int b = blk >> 10;
  int pb = (blk & 1023) << 4;
  int y = pb >> 7;
  int xb = pb & 127;
  int tid = threadIdx.x;

  if (tid < 144) {
    int k = tid >> 4, p = tid & 15;
    int xx = xb + p;
    const float* omb = omT + ((size_t)b * HW + (size_t)y * Wd + xx) * 64;
    float dy = omb[2 * k];
    float dx = omb[2 * k + 1];
    float mv = omb[18 + k];
    mv = 1.f / (1.f + __expf(-mv));
    float py = (float)(y + (k / 3) - 1) + dy;
    float px = (float)(xx + (k % 3) - 1) + dx;
    float fy = floorf(py), fx = floorf(px);
    gy0[tid] = (int)fy; gx0[tid] = (int)fx;
    gwy[tid] = py - fy; gwx[tid] = px - fx;
    gm[tid] = mv;
  }
  __syncthreads();

  {
    int c = tid & 63, q = tid >> 6;
    const float* xbp = xT + ((size_t)b * HW) * 64 + c;
    for (int k = 0; k < 9; ++k) {
      #pragma unroll
      for (int i = 0; i < 4; ++i) {
        int p = q * 4 + i;
        int gi = k * 16 + p;
        int yy = gy0[gi], xc = gx0[gi];
        float wy = gwy[gi], wx = gwx[gi];
        bool y0v = (unsigned)yy < 128u, y1v = (unsigned)(yy + 1) < 128u;
        bool x0v = (unsigned)xc < 128u, x1v = (unsigned)(xc + 1) < 128u;
        long off = ((long)yy * Wd + xc) * 64;
        float v00 = (y0v && x0v) ? xbp[off] : 0.f;
        float v01 = (y0v && x1v) ? xbp[off + 64] : 0.f;
        float v10 = (y1v && x0v) ? xbp[off + Wd * 64] : 0.f;
        float v11 = (y1v && x1v) ? xbp[off + Wd * 64 + 64] : 0.f;
        float vs = (v00 * (1.f - wx) + v01 * wx) * (1.f - wy)
                 + (v10 * (1.f - wx) + v11 * wx) * wy;
        SM[p * 580 + k * 64 + c] = vs * gm[gi];
      }
    }
  }
  __syncthreads();

  int pg = tid & 3;
  int cg = (tid >> 2) & 7;
  int r = tid >> 5;
  float acc[4][8];
  #pragma unroll
  for (int i = 0; i < 4; ++i)
    #pragma unroll
    for (int j = 0; j < 8; ++j) acc[i][j] = 0.f;

  for (int k = 0; k < 9; ++k) {
    const float* wkp = wdT + k * 4096;
    #pragma unroll
    for (int q4 = 0; q4 < 2; ++q4) {
      int cib = r * 8 + q4 * 4;
      float svf[4][4];
      #pragma unroll
      for (int i = 0; i < 4; ++i) {
        float4 t4 = *reinterpret_cast<const float4*>(
            &SM[(pg * 4 + i) * 580 + k * 64 + cib]);
        svf[i][0] = t4.x; svf[i][1] = t4.y; svf[i][2] = t4.z; svf[i][3] = t4.w;
      }
      float wlo[4][4], whi[4][4];
      #pragma unroll
      for (int jj = 0; jj < 4; ++jj) {
        const float* wrow = wkp + (cib + jj) * 64 + cg * 8;
        float4 a = *reinterpret_cast<const float4*>(wrow);
        float4 c4 = *reinterpret_cast<const float4*>(wrow + 4);
        wlo[jj][0] = a.x; wlo[jj][1] = a.y; wlo[jj][2] = a.z; wlo[jj][3] = a.w;
        whi[jj][0] = c4.x; whi[jj][1] = c4.y; whi[jj][2] = c4.z; whi[jj][3] = c4.w;
      }
      #pragma unroll
      for (int i = 0; i < 4; ++i)
        #pragma unroll
        for (int jj = 0; jj < 4; ++jj) {
          float s = svf[i][jj];
          #pragma unroll
          for (int j = 0; j < 4; ++j) {
            acc[i][j]     += s * wlo[jj][j];
            acc[i][j + 4] += s * whi[jj][j];
          }
        }
    }
  }
  __syncthreads();

  {
    int T = cg * 4 + pg;
    float* rb = &SM[T * 257 + r * 32];
    #pragma unroll
    for (int i = 0; i < 4; ++i)
      #pragma unroll
      for (int j = 0; j < 8; ++j)
        rb[i * 8 + j] = acc[i][j];
  }
  __syncthreads();

  int p = tid & 15, cg2 = tid >> 4;
  {
    int T = (cg2 >> 1) * 4 + (p >> 2);
    int ebase = (p & 3) * 8 + (cg2 & 1) * 4;
    #pragma unroll
    for (int j = 0; j < 4; ++j) {
      float s = 0.f;
      #pragma unroll
      for (int rr = 0; rr < 8; ++rr)
        s += SM[T * 257 + rr * 32 + ebase + j];
      s += bd[cg2 * 4 + j];
      s = s >= 0.f ? s : 0.1f * s;
      SM[8240 + p * 65 + cg2 * 4 + j] = s;
    }
  }
  __syncthreads();

  {
    float a0 = b1[cg2 * 4], a1 = b1[cg2 * 4 + 1];
    float a2 = b1[cg2 * 4 + 2], a3 = b1[cg2 * 4 + 3];
    const float* wp = w1T + cg2 * 4;
    const float* sd = &SM[8240 + p * 65];
    #pragma unroll 8
    for (int co = 0; co < 64; ++co) {
      float dv = sd[co];
      float4 wv = *reinterpret_cast<const float4*>(wp + co * 64);
      a0 += dv * wv.x; a1 += dv * wv.y; a2 += dv * wv.z; a3 += dv * wv.w;
    }
    float r0 = a0 >= 0.f ? a0 : 0.1f * a0;
    float r1 = a1 >= 0.f ? a1 : 0.1f * a1;
    float r2 = a2 >= 0.f ? a2 : 0.1f * a2;
    float r3 = a3 >= 0.f ? a3 : 0.1f * a3;
    float4 o4 = make_float4(r0, r1, r2, r3);
    *reinterpret_cast<float4*>(
        &out[((size_t)b * HW + pb + p) * 64 + cg2 * 4]) = o4;
  }
}

// ---------------------------------------------------------------------------
extern "C" void kernel_launch(void* const* d_in, const int* in_sizes, int n_in,
                              void* d_out, int out_size, void* d_ws, size_t ws_size,
                              hipStream_t stream) {
  (void)in_sizes; (void)n_in; (void)out_size; (void)ws_size;
  const float* x       = (const float*)d_in[0];
  const float* x_ref   = (const float*)d_in[1];
  const float* amp     = (const float*)d_in[2];
  const float* new_inp = (const float*)d_in[3];
  const float* w_off1  = (const float*)d_in[4];
  const float* b_off1  = (const float*)d_in[5];
  const float* w_off2  = (const float*)d_in[6];
  const float* b_off2  = (const float*)d_in[7];
  const float* w_om    = (const float*)d_in[8];
  const float* b_om    = (const float*)d_in[9];
  const float* w_dcn   = (const float*)d_in[10];
  const float* b_dcn   = (const float*)d_in[11];
  const float* w_1x1   = (const float*)d_in[12];
  const float* b_1x1   = (const float*)d_in[13];
  const float* w_3x3   = (const float*)d_in[14];
  const float* b_3x3   = (const float*)d_in[15];
  float* out = (float*)d_out;

  float* ws = (float*)d_ws;
  float* A  = ws;                 // 16.8MB: feat; later xT(8.4) + niT(8.4)
  float* B  = A + 4194304;        // 16.8MB: featT; later omT(8.4)
  float* C  = B + 4194304;        // 8.4MB: buf1T; later d2T
  float* D  = C + 2097152;        // 8.4MB: buf2T
  float* W  = D + 2097152;        // weights: 262,208 floats
  float* feat  = A;
  float* xT    = A;
  float* niT   = A + 2097152;
  float* featT = B;
  float* omT   = B;
  float* buf1T = C;
  float* d2T   = C;
  float* buf2T = D;
  float* wG1 = W;                 // 73728
  float* wG2 = wG1 + 73728;       // 36864
  float* wGm = wG2 + 36864;       // 36864
  float* wG3 = wGm + 36864;       // 73728
  float* wdT = wG3 + 73728;       // 36864
  float* w1T = wdT + 36864;       // 4096
  float* bmp = w1T + 4096;        // 64

  // 0) weight prep
  hipLaunchKernelGGL(prep_gemm, dim3(1025), dim3(256), 0, stream,
                     w_off1, w_off2, w_om, w_3x3, w_dcn, w_1x1, b_om,
                     wG1, wG2, wGm, wG3, wdT, w1T, bmp);
  // 1) FFT amplitude swap -> feat (channel-major)
  hipLaunchKernelGGL(fft_amp_kernel, dim3(256), dim3(NT_FFT), 0, stream,
                     x, x_ref, amp, feat);
  // 2) feat -> featT (pixel-major)
  hipLaunchKernelGGL((transpose_pm<128>), dim3(512), dim3(256), 0, stream,
                     feat, featT);
  // 3) x -> xT, new_inp -> niT (into now-dead feat region)
  hipLaunchKernelGGL((transpose_pm<64>), dim3(512), dim3(256), 0, stream,
                     x, xT);
  hipLaunchKernelGGL((transpose_pm<64>), dim3(512), dim3(256), 0, stream,
                     new_inp, niT);
  // 4) conv1 (128->64) + lrelu
  hipLaunchKernelGGL((conv_gemm<128, false, 0>), dim3(2048), dim3(256), 0,
                     stream, featT, (const float*)nullptr, wG1, b_off1,
                     buf1T, 1);
  // 5) conv2 (64->64) + lrelu
  hipLaunchKernelGGL((conv_gemm<64, false, 0>), dim3(2048), dim3(256), 0,
                     stream, buf1T, (const float*)nullptr, wG2, b_off2,
                     buf2T, 1);
  // 6) om conv (64->64 padded, co>=27 zero) into featT region (dead)
  hipLaunchKernelGGL((conv_gemm<64, false, 0>), dim3(2048), dim3(256), 0,
                     stream, buf2T, (const float*)nullptr, wGm, bmp,
                     omT, 0);
  // 7) deform + fused 1x1 -> d2T (pixel-major, overwrites buf1T)
  hipLaunchKernelGGL(deform_v3, dim3(2048), dim3(256), 0, stream,
                     xT, omT, wdT, b_dcn, w1T, b_1x1, d2T);
  // 8) final conv on concat([d2T, niT]) -> out (channel-major)
  hipLaunchKernelGGL((conv_gemm<128, true, 1>), dim3(2048), dim3(256), 0,
                     stream, d2T, niT, wG3, b_3x3, out, 0);
}

// Round 12
// 322.311 us; speedup vs baseline: 2.6882x; 1.5343x over previous
//
#include <hip/hip_runtime.h>
#include <hip/hip_bf16.h>
#include <math.h>

#define HW 16384
#define Wd 128
#define NT_FFT 1024

typedef __attribute__((ext_vector_type(8))) short bf16x8;
typedef __attribute__((ext_vector_type(4))) float f32x4;

__device__ __forceinline__ short f2bf(float f) {
  unsigned u = __float_as_uint(f);
  unsigned r = (u + 0x7FFFu + ((u >> 16) & 1u)) >> 16;
  return (short)r;
}

// ---------------------------------------------------------------------------
// FFT amplitude-replacement kernel (unchanged): one block per plane.
// ---------------------------------------------------------------------------
__device__ __forceinline__ void fft_dim(float* re, float* im,
                                        const float* twc, const float* tws,
                                        int tid, int cols)
{
  for (int idx = tid; idx < 16384; idx += NT_FFT) {
    int f = idx & 127, g = idx >> 7;
    int r = cols ? f : g;
    int i = cols ? g : f;
    int j = (int)(__brev((unsigned)i) >> 25);
    if (i < j) {
      int e0 = cols ? (i * 128 + r) : (r * 128 + i);
      int e1 = cols ? (j * 128 + r) : (r * 128 + j);
      float t0 = re[e0]; re[e0] = re[e1]; re[e1] = t0;
      float t1 = im[e0]; im[e0] = im[e1]; im[e1] = t1;
    }
  }
  __syncthreads();
  for (int s = 0; s < 7; ++s) {
    int half = 1 << s;
    for (int idx = tid; idx < 8192; idx += NT_FFT) {
      int t, r;
      if (cols) { r = idx & 127; t = idx >> 7; }
      else      { r = idx >> 6;  t = idx & 63; }
      int pos = t & (half - 1);
      int i0 = ((t >> s) << (s + 1)) + pos;
      int i1 = i0 + half;
      int e0 = cols ? (i0 * 128 + r) : (r * 128 + i0);
      int e1 = cols ? (i1 * 128 + r) : (r * 128 + i1);
      int tj = pos << (6 - s);
      float cs = twc[tj], sn = tws[tj];
      float br = re[e1], bi = im[e1];
      float tr = br * cs - bi * sn;
      float ti = br * sn + bi * cs;
      float ar = re[e0], ai = im[e0];
      re[e0] = ar + tr; im[e0] = ai + ti;
      re[e1] = ar - tr; im[e1] = ai - ti;
    }
    __syncthreads();
  }
}

__global__ __launch_bounds__(NT_FFT) void fft_amp_kernel(
    const float* __restrict__ x, const float* __restrict__ xref,
    const float* __restrict__ amp, float* __restrict__ feat)
{
  __shared__ float sre[16384];
  __shared__ float sim[16384];
  __shared__ float twc[64];
  __shared__ float tws[64];
  int tid = threadIdx.x;
  int blk = blockIdx.x;          // 0..255
  int tensor = blk >> 7;         // 0 = x, 1 = x_ref
  int plane = blk & 127;         // b*64 + c
  const float* src = (tensor ? xref : x) + (size_t)plane * HW;
  if (tid < 64) {
    float ang = -6.283185307179586f * (float)tid / 128.f;
    float sn, cs;
    __sincosf(ang, &sn, &cs);
    twc[tid] = cs; tws[tid] = sn;
  }
  for (int i = tid; i < 16384; i += NT_FFT) { sre[i] = src[i]; sim[i] = 0.f; }
  __syncthreads();
  fft_dim(sre, sim, twc, tws, tid, 0);
  fft_dim(sre, sim, twc, tws, tid, 1);
  const float* ampb = amp + (size_t)plane * (128 * 65);
  for (int idx = tid; idx < 16384; idx += NT_FFT) {
    int ky = idx >> 7, kx = idx & 127;
    float A = (kx <= 64) ? ampb[ky * 65 + kx]
                         : ampb[((128 - ky) & 127) * 65 + (128 - kx)];
    float th = atan2f(sim[idx], sre[idx]);
    float sn, cs;
    __sincosf(th, &sn, &cs);
    sre[idx] = A * cs;
    sim[idx] = -A * sn;   // conj
  }
  __syncthreads();
  fft_dim(sre, sim, twc, tws, tid, 0);
  fft_dim(sre, sim, twc, tws, tid, 1);
  int b = plane >> 6, c = plane & 63;
  float* dst = feat + ((size_t)b * 128 + tensor * 64 + c) * HW;
  for (int i = tid; i < 16384; i += NT_FFT) dst[i] = sre[i] * (1.f / 16384.f);
}

// ---------------------------------------------------------------------------
// Transpose [b][C][HW] -> [b][HW][C] (pixel-major), 64-px chunks.
// ---------------------------------------------------------------------------
template<int C>
__global__ __launch_bounds__(256) void transpose_pm(
    const float* __restrict__ src, float* __restrict__ dst)
{
  __shared__ float t[64][C + 4];
  int blk = blockIdx.x;
  int b = blk >> 8;
  int pb = (blk & 255) << 6;
  int tid = threadIdx.x;
  int l = tid & 63;
  #pragma unroll
  for (int it = 0; it < C / 4; ++it) {
    int c = (tid >> 6) + it * 4;
    t[l][c] = src[((size_t)b * C + c) * HW + pb + l];
  }
  __syncthreads();
  constexpr int CG = C / 4;
  constexpr int PXI = 256 / CG;
  int c4 = (tid & (CG - 1)) * 4;
  int p0 = tid / CG;
  #pragma unroll
  for (int it = 0; it < 64 / PXI; ++it) {
    int p = p0 + it * PXI;
    float4 v = make_float4(t[p][c4], t[p][c4 + 1], t[p][c4 + 2], t[p][c4 + 3]);
    *reinterpret_cast<float4*>(&dst[((size_t)b * HW + pb + p) * C + c4]) = v;
  }
}

// ---------------------------------------------------------------------------
// Weight prep: MFMA B-fragment packs wB*[k][ci/8][co][8ci] (bf16), plus
// fp32 wdT[k][ci][co], w1T[co][co2], padded om bias.
// ---------------------------------------------------------------------------
__global__ __launch_bounds__(256) void prep_gemm(
    const float* __restrict__ w_off1, const float* __restrict__ w_off2,
    const float* __restrict__ w_om, const float* __restrict__ w_3x3,
    const float* __restrict__ wd, const float* __restrict__ w1,
    const float* __restrict__ b_om,
    short* __restrict__ wB1, short* __restrict__ wB2,
    short* __restrict__ wBm, short* __restrict__ wB3,
    float* __restrict__ wdT, float* __restrict__ w1T, float* __restrict__ bmp)
{
  int i = blockIdx.x * 256 + threadIdx.x;
  if (i < 73728) {                       // wB1[9][16][64][8], CIN=128
    int e = i & 7, co = (i >> 3) & 63, ci8 = (i >> 9) & 15, k = i >> 13;
    int ci = ci8 * 8 + e;
    wB1[i] = f2bf(w_off1[((size_t)co * 128 + ci) * 9 + k]);
  } else if (i < 110592) {               // wB2[9][8][64][8], CIN=64
    int j = i - 73728;
    int e = j & 7, co = (j >> 3) & 63, ci8 = (j >> 9) & 7, k = j >> 12;
    int ci = ci8 * 8 + e;
    wB2[j] = f2bf(w_off2[((size_t)co * 64 + ci) * 9 + k]);
  } else if (i < 147456) {               // wBm[9][8][64][8], co>=27 zero
    int j = i - 110592;
    int e = j & 7, co = (j >> 3) & 63, ci8 = (j >> 9) & 7, k = j >> 12;
    int ci = ci8 * 8 + e;
    wBm[j] = (co < 27) ? f2bf(w_om[((size_t)co * 64 + ci) * 9 + k]) : (short)0;
  } else if (i < 221184) {               // wB3[9][16][64][8], CIN=128
    int j = i - 147456;
    int e = j & 7, co = (j >> 3) & 63, ci8 = (j >> 9) & 15, k = j >> 13;
    int ci = ci8 * 8 + e;
    wB3[j] = f2bf(w_3x3[((size_t)co * 128 + ci) * 9 + k]);
  } else if (i < 258048) {               // wdT[k][ci][co] fp32
    int j = i - 221184;
    int k = j >> 12, ci = (j >> 6) & 63, co = j & 63;
    wdT[j] = wd[co * 576 + ci * 9 + k];
  } else if (i < 262144) {               // w1T[co][co2] fp32
    int j = i - 258048;
    w1T[j] = w1[(j & 63) * 64 + (j >> 6)];
  } else if (i < 262208) {
    int j = i - 262144;
    bmp[j] = (j < 27) ? b_om[j] : 0.f;
  }
}

// ---------------------------------------------------------------------------
// conv_mfma: 3x3 conv as im2col GEMM on the bf16 matrix cores.
// Block: 16 px x 64 co; 4 waves, each owns a 16x16 D tile (co tile w*16).
// A: im2col window in LDS (bf16, +8-short pad); per K-step one ds_read_b128.
// B: prepacked fragment from global (16B contiguous, L1-hit).
// mfma_f32_16x16x32_bf16; C/D: col=lane&15 (co), row=(lane>>4)*4+j (px).
// One barrier per block. OUTMODE 0: pixel-major; 1: channel-major float4.
// ---------------------------------------------------------------------------
template<int CIN, bool CONCAT, int OUTMODE>
__global__ __launch_bounds__(256) void conv_mfma(
    const float* __restrict__ a1, const float* __restrict__ a2,
    const short* __restrict__ wB, const float* __restrict__ bias,
    float* __restrict__ out, int lrelu)
{
  constexpr int CP = CIN + 8;            // bf16 pad: row stride 272/144 B
  __shared__ __align__(16) short win[3 * 20 * CP];
  int blk = blockIdx.x;
  int b = blk >> 10;
  int pb = (blk & 1023) << 4;
  int y = pb >> 7;
  int xb = pb & 127;
  int tid = threadIdx.x;

  // stage im2col window as bf16: rows y-1..y+1, cols xb-1..xb+16
  {
    constexpr int CF = CIN / 4;
    constexpr int NF4 = 3 * 18 * CF;
    for (int i = tid; i < NF4; i += 256) {
      int ci4 = (i % CF) * 4;
      int t = i / CF;
      int col = t % 18;
      int row = t / 18;
      int yy = y - 1 + row;
      int xx = xb - 1 + col;
      float4 v = make_float4(0.f, 0.f, 0.f, 0.f);
      if ((unsigned)yy < 128u && (unsigned)xx < 128u) {
        size_t pix = (size_t)b * HW + (size_t)yy * Wd + xx;
        if (CONCAT)
          v = (ci4 < 64)
              ? *reinterpret_cast<const float4*>(a1 + pix * 64 + ci4)
              : *reinterpret_cast<const float4*>(a2 + pix * 64 + (ci4 - 64));
        else
          v = *reinterpret_cast<const float4*>(a1 + pix * CIN + ci4);
      }
      unsigned p0 = (unsigned)(unsigned short)f2bf(v.x)
                  | ((unsigned)(unsigned short)f2bf(v.y) << 16);
      unsigned p1 = (unsigned)(unsigned short)f2bf(v.z)
                  | ((unsigned)(unsigned short)f2bf(v.w) << 16);
      *reinterpret_cast<uint2*>(&win[(row * 20 + col) * CP + ci4]) =
          make_uint2(p0, p1);
    }
  }
  __syncthreads();

  int lane = tid & 63;
  int w = tid >> 6;            // wave id: co tile base w*16
  int m16 = lane & 15;
  int kq = lane >> 4;          // 0..3
  f32x4 acc = {0.f, 0.f, 0.f, 0.f};

  for (int k = 0; k < 9; ++k) {
    int dy = k / 3, dx = k - dy * 3;
    int arow = (dy * 20 + m16 + dx) * CP;
    const short* wkB = wB + (size_t)k * (CIN / 8) * 512;
    #pragma unroll
    for (int s = 0; s < CIN / 32; ++s) {
      int ci0 = s * 32;
      bf16x8 av = *reinterpret_cast<const bf16x8*>(&win[arow + ci0 + kq * 8]);
      bf16x8 bv = *reinterpret_cast<const bf16x8*>(
          wkB + (((ci0 >> 3) + kq) * 64 + w * 16 + m16) * 8);
      acc = __builtin_amdgcn_mfma_f32_16x16x32_bf16(av, bv, acc, 0, 0, 0);
    }
  }

  // epilogue: bias + lrelu + store
  int co = w * 16 + m16;
  float bvv = bias[co];
  if (OUTMODE == 0) {
    #pragma unroll
    for (int j = 0; j < 4; ++j) {
      int m = kq * 4 + j;
      float v = acc[j] + bvv;
      if (lrelu) v = v >= 0.f ? v : 0.1f * v;
      out[((size_t)b * HW + pb + m) * 64 + co] = v;
    }
  } else {
    float4 o4;
    float v0 = acc[0] + bvv, v1 = acc[1] + bvv;
    float v2 = acc[2] + bvv, v3 = acc[3] + bvv;
    if (lrelu) {
      v0 = v0 >= 0.f ? v0 : 0.1f * v0;
      v1 = v1 >= 0.f ? v1 : 0.1f * v1;
      v2 = v2 >= 0.f ? v2 : 0.1f * v2;
      v3 = v3 >= 0.f ? v3 : 0.1f * v3;
    }
    o4 = make_float4(v0, v1, v2, v3);
    *reinterpret_cast<float4*>(
        &out[((size_t)b * 64 + co) * HW + pb + kq * 4]) = o4;
  }
}

// ---------------------------------------------------------------------------
// Deformable conv + fused 1x1, v3 (unchanged from r11).
// ---------------------------------------------------------------------------
__global__ __launch_bounds__(256) void deform_v3(
    const float* __restrict__ xT, const float* __restrict__ omT,
    const float* __restrict__ wdT, const float* __restrict__ bd,
    const float* __restrict__ w1T, const float* __restrict__ b1,
    float* __restrict__ out)
{
  __shared__ float SM[9344];
  __shared__ int   gy0[144];
  __shared__ int   gx0[144];
  __shared__ float gwy[144];
  __shared__ float gwx[144];
  __shared__ float gm[144];

  int blk = blockIdx.x;
  int b = blk >> 10;
  int pb = (blk & 1023) << 4;
  int y = pb >> 7;
  int xb = pb & 127;
  int tid = threadIdx.x;

  if (tid < 144) {
    int k = tid >> 4, p = tid & 15;
    int xx = xb + p;
    const float* omb = omT + ((size_t)b * HW + (size_t)y * Wd + xx) * 64;
    float dy = omb[2 * k];
    float dx = omb[2 * k + 1];
    float mv = omb[18 + k];
    mv = 1.f / (1.f + __expf(-mv));
    float py = (float)(y + (k / 3) - 1) + dy;
    float px = (float)(xx + (k % 3) - 1) + dx;
    float fy = floorf(py), fx = floorf(px);
    gy0[tid] = (int)fy; gx0[tid] = (int)fx;
    gwy[tid] = py - fy; gwx[tid] = px - fx;
    gm[tid] = mv;
  }
  __syncthreads();

  {
    int c = tid & 63, q = tid >> 6;
    const float* xbp = xT + ((size_t)b * HW) * 64 + c;
    for (int k = 0; k < 9; ++k) {
      #pragma unroll
      for (int i = 0; i < 4; ++i) {
        int p = q * 4 + i;
        int gi = k * 16 + p;
        int yy = gy0[gi], xc = gx0[gi];
        float wy = gwy[gi], wx = gwx[gi];
        bool y0v = (unsigned)yy < 128u, y1v = (unsigned)(yy + 1) < 128u;
        bool x0v = (unsigned)xc < 128u, x1v = (unsigned)(xc + 1) < 128u;
        long off = ((long)yy * Wd + xc) * 64;
        float v00 = (y0v && x0v) ? xbp[off] : 0.f;
        float v01 = (y0v && x1v) ? xbp[off + 64] : 0.f;
        float v10 = (y1v && x0v) ? xbp[off + Wd * 64] : 0.f;
        float v11 = (y1v && x1v) ? xbp[off + Wd * 64 + 64] : 0.f;
        float vs = (v00 * (1.f - wx) + v01 * wx) * (1.f - wy)
                 + (v10 * (1.f - wx) + v11 * wx) * wy;
        SM[p * 580 + k * 64 + c] = vs * gm[gi];
      }
    }
  }
  __syncthreads();

  int pg = tid & 3;
  int cg = (tid >> 2) & 7;
  int r = tid >> 5;
  float acc[4][8];
  #pragma unroll
  for (int i = 0; i < 4; ++i)
    #pragma unroll
    for (int j = 0; j < 8; ++j) acc[i][j] = 0.f;

  for (int k = 0; k < 9; ++k) {
    const float* wkp = wdT + k * 4096;
    #pragma unroll
    for (int q4 = 0; q4 < 2; ++q4) {
      int cib = r * 8 + q4 * 4;
      float svf[4][4];
      #pragma unroll
      for (int i = 0; i < 4; ++i) {
        float4 t4 = *reinterpret_cast<const float4*>(
            &SM[(pg * 4 + i) * 580 + k * 64 + cib]);
        svf[i][0] = t4.x; svf[i][1] = t4.y; svf[i][2] = t4.z; svf[i][3] = t4.w;
      }
      float wlo[4][4], whi[4][4];
      #pragma unroll
      for (int jj = 0; jj < 4; ++jj) {
        const float* wrow = wkp + (cib + jj) * 64 + cg * 8;
        float4 a = *reinterpret_cast<const float4*>(wrow);
        float4 c4 = *reinterpret_cast<const float4*>(wrow + 4);
        wlo[jj][0] = a.x; wlo[jj][1] = a.y; wlo[jj][2] = a.z; wlo[jj][3] = a.w;
        whi[jj][0] = c4.x; whi[jj][1] = c4.y; whi[jj][2] = c4.z; whi[jj][3] = c4.w;
      }
      #pragma unroll
      for (int i = 0; i < 4; ++i)
        #pragma unroll
        for (int jj = 0; jj < 4; ++jj) {
          float s = svf[i][jj];
          #pragma unroll
          for (int j = 0; j < 4; ++j) {
            acc[i][j]     += s * wlo[jj][j];
            acc[i][j + 4] += s * whi[jj][j];
          }
        }
    }
  }
  __syncthreads();

  {
    int T = cg * 4 + pg;
    float* rb = &SM[T * 257 + r * 32];
    #pragma unroll
    for (int i = 0; i < 4; ++i)
      #pragma unroll
      for (int j = 0; j < 8; ++j)
        rb[i * 8 + j] = acc[i][j];
  }
  __syncthreads();

  int p = tid & 15, cg2 = tid >> 4;
  {
    int T = (cg2 >> 1) * 4 + (p >> 2);
    int ebase = (p & 3) * 8 + (cg2 & 1) * 4;
    #pragma unroll
    for (int j = 0; j < 4; ++j) {
      float s = 0.f;
      #pragma unroll
      for (int rr = 0; rr < 8; ++rr)
        s += SM[T * 257 + rr * 32 + ebase + j];
      s += bd[cg2 * 4 + j];
      s = s >= 0.f ? s : 0.1f * s;
      SM[8240 + p * 65 + cg2 * 4 + j] = s;
    }
  }
  __syncthreads();

  {
    float a0 = b1[cg2 * 4], a1 = b1[cg2 * 4 + 1];
    float a2 = b1[cg2 * 4 + 2], a3 = b1[cg2 * 4 + 3];
    const float* wp = w1T + cg2 * 4;
    const float* sd = &SM[8240 + p * 65];
    #pragma unroll 8
    for (int co = 0; co < 64; ++co) {
      float dv = sd[co];
      float4 wv = *reinterpret_cast<const float4*>(wp + co * 64);
      a0 += dv * wv.x; a1 += dv * wv.y; a2 += dv * wv.z; a3 += dv * wv.w;
    }
    float r0 = a0 >= 0.f ? a0 : 0.1f * a0;
    float r1 = a1 >= 0.f ? a1 : 0.1f * a1;
    float r2 = a2 >= 0.f ? a2 : 0.1f * a2;
    float r3 = a3 >= 0.f ? a3 : 0.1f * a3;
    float4 o4 = make_float4(r0, r1, r2, r3);
    *reinterpret_cast<float4*>(
        &out[((size_t)b * HW + pb + p) * 64 + cg2 * 4]) = o4;
  }
}

// ---------------------------------------------------------------------------
extern "C" void kernel_launch(void* const* d_in, const int* in_sizes, int n_in,
                              void* d_out, int out_size, void* d_ws, size_t ws_size,
                              hipStream_t stream) {
  (void)in_sizes; (void)n_in; (void)out_size; (void)ws_size;
  const float* x       = (const float*)d_in[0];
  const float* x_ref   = (const float*)d_in[1];
  const float* amp     = (const float*)d_in[2];
  const float* new_inp = (const float*)d_in[3];
  const float* w_off1  = (const float*)d_in[4];
  const float* b_off1  = (const float*)d_in[5];
  const float* w_off2  = (const float*)d_in[6];
  const float* b_off2  = (const float*)d_in[7];
  const float* w_om    = (const float*)d_in[8];
  const float* b_om    = (const float*)d_in[9];
  const float* w_dcn   = (const float*)d_in[10];
  const float* b_dcn   = (const float*)d_in[11];
  const float* w_1x1   = (const float*)d_in[12];
  const float* b_1x1   = (const float*)d_in[13];
  const float* w_3x3   = (const float*)d_in[14];
  const float* b_3x3   = (const float*)d_in[15];
  float* out = (float*)d_out;

  float* ws = (float*)d_ws;
  float* A  = ws;                 // feat; later xT + niT
  float* B  = A + 4194304;        // featT; later omT
  float* C  = B + 4194304;        // buf1T; later d2T
  float* D  = C + 2097152;        // buf2T
  float* W  = D + 2097152;        // weight region
  float* feat  = A;
  float* xT    = A;
  float* niT   = A + 2097152;
  float* featT = B;
  float* omT   = B;
  float* buf1T = C;
  float* d2T   = C;
  float* buf2T = D;
  float* wdT = W;                 // 36,864 f
  float* w1T = wdT + 36864;       // 4,096 f
  float* bmp = w1T + 4096;        // 64 f
  short* wB1 = (short*)(bmp + 64);   // 73,728 bf16
  short* wB2 = wB1 + 73728;          // 36,864
  short* wBm = wB2 + 36864;          // 36,864
  short* wB3 = wBm + 36864;          // 73,728

  // 0) weight prep
  hipLaunchKernelGGL(prep_gemm, dim3(1025), dim3(256), 0, stream,
                     w_off1, w_off2, w_om, w_3x3, w_dcn, w_1x1, b_om,
                     wB1, wB2, wBm, wB3, wdT, w1T, bmp);
  // 1) FFT amplitude swap -> feat (channel-major)
  hipLaunchKernelGGL(fft_amp_kernel, dim3(256), dim3(NT_FFT), 0, stream,
                     x, x_ref, amp, feat);
  // 2) feat -> featT (pixel-major)
  hipLaunchKernelGGL((transpose_pm<128>), dim3(512), dim3(256), 0, stream,
                     feat, featT);
  // 3) x -> xT, new_inp -> niT (into now-dead feat region)
  hipLaunchKernelGGL((transpose_pm<64>), dim3(512), dim3(256), 0, stream,
                     x, xT);
  hipLaunchKernelGGL((transpose_pm<64>), dim3(512), dim3(256), 0, stream,
                     new_inp, niT);
  // 4) conv1 (128->64) + lrelu  [MFMA]
  hipLaunchKernelGGL((conv_mfma<128, false, 0>), dim3(2048), dim3(256), 0,
                     stream, featT, (const float*)nullptr, wB1, b_off1,
                     buf1T, 1);
  // 5) conv2 (64->64) + lrelu  [MFMA]
  hipLaunchKernelGGL((conv_mfma<64, false, 0>), dim3(2048), dim3(256), 0,
                     stream, buf1T, (const float*)nullptr, wB2, b_off2,
                     buf2T, 1);
  // 6) om conv (64->64 padded) -> omT  [MFMA]
  hipLaunchKernelGGL((conv_mfma<64, false, 0>), dim3(2048), dim3(256), 0,
                     stream, buf2T, (const float*)nullptr, wBm, bmp,
                     omT, 0);
  // 7) deform + fused 1x1 -> d2T (fp32, unchanged)
  hipLaunchKernelGGL(deform_v3, dim3(2048), dim3(256), 0, stream,
                     xT, omT, wdT, b_dcn, w1T, b_1x1, d2T);
  // 8) final conv on concat([d2T, niT]) -> out (channel-major)  [MFMA]
  hipLaunchKernelGGL((conv_mfma<128, true, 1>), dim3(2048), dim3(256), 0,
                     stream, d2T, niT, wB3, b_3x3, out, 0);
}